// Round 9
// baseline (195.772 us; speedup 1.0000x reference)
//
#include <hip/hip_runtime.h>

typedef __bf16 bf16;
typedef __bf16 bf16x4 __attribute__((ext_vector_type(4)));
typedef __bf16 bf16x8 __attribute__((ext_vector_type(8)));
typedef float floatx4 __attribute__((ext_vector_type(4)));

#define EPS 1.1920929e-07f
// q scale = D^-0.5 * log2(e) folded together (D=64 -> 0.125)
#define QSCALE (0.125f * 1.44269504088896f)
// fixed softmax shift: |q_eff . k| <= ||q_eff||*||k|| = (8*QSCALE)*8 = 11.5416
#define SHIFT_C 11.5416f

__device__ __forceinline__ floatx4 mfma16(bf16x8 a, bf16x8 b, floatx4 c) {
  return __builtin_amdgcn_mfma_f32_16x16x32_bf16(a, b, c, 0, 0, 0);
}

// async 16B global->LDS: HW writes ldsbase + lane*16; gptr is per-lane
__device__ __forceinline__ void gload16(const void* g, void* l) {
  __builtin_amdgcn_global_load_lds((const __attribute__((address_space(1))) unsigned int*)g,
                                   (__attribute__((address_space(3))) unsigned int*)l, 16, 0, 0);
}

// ---------------- merged prep: cast+gate (blocks <4096) | weight pack (blocks >=4096) ----
__global__ void prep_kernel(const float* __restrict__ x, const float* __restrict__ wgate,
                            const float* __restrict__ Wq, const float* __restrict__ Wk,
                            const float* __restrict__ Wv, const float* __restrict__ Wproj,
                            bf16* __restrict__ xb, float* __restrict__ gate,
                            bf16* __restrict__ out_qkv, bf16* __restrict__ out_proj) {
  __shared__ float tile[32][33];
  const int tid = threadIdx.x;
  if (blockIdx.x < 4096) {
    // ---- cast + gate: one block per token ----
    int t = blockIdx.x;
    const float* xr = x + (size_t)t * 1024;
    float4 v = *(const float4*)(xr + tid * 4);
    bf16x4 o = {(bf16)v.x, (bf16)v.y, (bf16)v.z, (bf16)v.w};
    *(bf16x4*)(xb + (size_t)t * 1024 + tid * 4) = o;
    if (tid < 64) {
      int c = (tid & 31) * 4;  // gate columns come from lanes 0..31 only
#pragma unroll
      for (int kv = 0; kv < 4; kv++) {
        float g = v.x * wgate[(c + 0) * 4 + kv] + v.y * wgate[(c + 1) * 4 + kv] +
                  v.z * wgate[(c + 2) * 4 + kv] + v.w * wgate[(c + 3) * 4 + kv];
        g += __shfl_xor(g, 1, 64);
        g += __shfl_xor(g, 2, 64);
        g += __shfl_xor(g, 4, 64);
        g += __shfl_xor(g, 8, 64);
        g += __shfl_xor(g, 16, 64);
        if (tid == 0) {
          int b = t >> 11, s = t & 2047;
          gate[((size_t)b * 4 + kv) * 2048 + s] = 2.f / (1.f + __expf(-g));
        }
      }
    }
  } else {
    // ---- weight pack: qkv (nx<48) + wproj (nx>=48) ----
    int j = blockIdx.x - 4096;
    int ky = j / 80;
    int nx = j - ky * 80;
    int k0 = ky * 32;
    int tx = tid & 31, ty = tid >> 5;
    if (nx < 48) {
      int n0 = nx * 32;
#pragma unroll
      for (int i = 0; i < 4; i++) {
        int k = k0 + ty + i * 8, n = n0 + tx;
        float v;
        if (n < 1024)      v = Wq[(size_t)k * 1024 + n];
        else if (n < 1280) v = Wk[(size_t)k * 256 + (n - 1024)];
        else               v = Wv[(size_t)k * 256 + (n - 1280)];
        tile[ty + i * 8][tx] = v;
      }
      __syncthreads();
#pragma unroll
      for (int i = 0; i < 4; i++) {
        int n = n0 + ty + i * 8, k = k0 + tx;
        out_qkv[(size_t)n * 1024 + k] = (bf16)tile[tx][ty + i * 8];
      }
    } else {
      int n0 = (nx - 48) * 32;
#pragma unroll
      for (int i = 0; i < 4; i++)
        tile[ty + i * 8][tx] = Wproj[(size_t)(k0 + ty + i * 8) * 1024 + n0 + tx];
      __syncthreads();
#pragma unroll
      for (int i = 0; i < 4; i++)
        out_proj[(size_t)(n0 + ty + i * 8) * 1024 + k0 + tx] = (bf16)tile[tx][ty + i * 8];
    }
  }
}

// ---------------- fused QKV GEMM: 128m x 64n tiles, BK=64, + RoPE/RMS/gate epilogue ----
// R6 known-good form. Single-buffer, 2 barriers/K-step, 24KB LDS, 3 blocks/CU.
// 1D grid 768 with XCD-chunked swizzle. n-tile: 0-15 Q heads, 16-19 K kv, 20-23 V kv.
__global__ __launch_bounds__(256) void qkv_gemm_kernel(const bf16* __restrict__ A,
                                                       const bf16* __restrict__ Bt,
                                                       const float* __restrict__ ve,
                                                       const float* __restrict__ cosb,
                                                       const float* __restrict__ sinb,
                                                       const float* __restrict__ gate,
                                                       bf16* __restrict__ Qb,
                                                       bf16* __restrict__ Kf,
                                                       bf16* __restrict__ Vf) {
  __shared__ __align__(16) char smem[24576];  // As 16K (2 halves x 128 x 32) + Bs 8K; epilogue Ep 128x72 bf16
  bf16* As = (bf16*)smem;
  bf16* Bs = (bf16*)(smem + 16384);
  bf16* Ep = (bf16*)smem;
  const int K = 1024;
  const int tid = threadIdx.x;
  // XCD-chunked bijective swizzle (768 % 8 == 0)
  const int orig = blockIdx.x;
  const int lid = (orig & 7) * 96 + (orig >> 3);
  const int tile = lid % 24;        // n-tile
  const int m0 = (lid / 24) * 128, n0 = tile * 64;
  const int w = tid >> 6, lane = tid & 63;
  const int q = lane >> 4, r0 = lane & 15;
  const int lrow = lane >> 2, lcol = (lane & 3) * 8;
  const int b = m0 >> 11, s0 = m0 & 2047;

  floatx4 acc[2][4];
#pragma unroll
  for (int i = 0; i < 2; i++)
#pragma unroll
    for (int j = 0; j < 4; j++) acc[i][j] = (floatx4){0.f, 0.f, 0.f, 0.f};

  for (int k0 = 0; k0 < K; k0 += 64) {
    __syncthreads();
    // A: 16 gloads (half s, row-block rb): wave w issues g = w*4..w*4+3
#pragma unroll
    for (int i = 0; i < 4; i++) {
      int g = w * 4 + i, s = g >> 3, rb = g & 7;
      gload16(A + (size_t)(m0 + rb * 16 + lrow) * K + k0 + s * 32 + lcol, &As[s * 4096 + rb * 512]);
    }
    // B: 8 gloads: wave w issues g = w*2, w*2+1
#pragma unroll
    for (int i = 0; i < 2; i++) {
      int g = w * 2 + i, s = g >> 2, rb = g & 3;
      gload16(Bt + (size_t)(n0 + rb * 16 + lrow) * K + k0 + s * 32 + lcol, &Bs[s * 2048 + rb * 512]);
    }
    __syncthreads();
#pragma unroll
    for (int s = 0; s < 2; s++) {
      bf16x8 af[2], bfr[4];
#pragma unroll
      for (int mt = 0; mt < 2; mt++) af[mt] = *(const bf16x8*)&As[s * 4096 + (w * 32 + mt * 16 + r0) * 32 + q * 8];
#pragma unroll
      for (int nt = 0; nt < 4; nt++) bfr[nt] = *(const bf16x8*)&Bs[s * 2048 + (nt * 16 + r0) * 32 + q * 8];
#pragma unroll
      for (int mt = 0; mt < 2; mt++)
#pragma unroll
        for (int nt = 0; nt < 4; nt++)
          acc[mt][nt] = mfma16(af[mt], bfr[nt], acc[mt][nt]);
    }
  }
  __syncthreads();  // all LDS reads done; Ep reuses the space

  // lane owns rows w*32 + mt*16 + q*4 + r (token - m0), d = nt*16 + r0
  if (tile < 16) {
    // ---- Q: rope -> rms -> *QSCALE -> Ep -> coalesced Qb copy ----
    const int h = tile;
#pragma unroll
    for (int mt = 0; mt < 2; mt++) {
      float rvv[4][4];
#pragma unroll
      for (int ntp = 0; ntp < 2; ntp++) {
        int d31 = ntp * 16 + r0;
#pragma unroll
        for (int r = 0; r < 4; r++) {
          int s = s0 + w * 32 + mt * 16 + q * 4 + r;
          float c = cosb[s * 32 + d31], sn = sinb[s * 32 + d31];
          float v1 = acc[mt][ntp][r], v2 = acc[mt][ntp + 2][r];
          rvv[ntp][r] = v1 * c + v2 * sn;
          rvv[ntp + 2][r] = v2 * c - v1 * sn;
        }
      }
#pragma unroll
      for (int r = 0; r < 4; r++) {
        float ss = 0.f;
#pragma unroll
        for (int nt = 0; nt < 4; nt++) ss += rvv[nt][r] * rvv[nt][r];
        ss += __shfl_xor(ss, 1, 64);
        ss += __shfl_xor(ss, 2, 64);
        ss += __shfl_xor(ss, 4, 64);
        ss += __shfl_xor(ss, 8, 64);
        float sc = rsqrtf(ss * (1.f / 64.f) + EPS) * QSCALE;
        int row = w * 32 + mt * 16 + q * 4 + r;
#pragma unroll
        for (int nt = 0; nt < 4; nt++)
          Ep[row * 72 + nt * 16 + r0] = (bf16)(rvv[nt][r] * sc);
      }
    }
    __syncthreads();
#pragma unroll
    for (int p = 0; p < 4; p++) {
      int g = p * 256 + tid;
      int row = g >> 3, chunk = g & 7;
      *(uint4*)&Qb[(((size_t)b * 16 + h) * 2048 + s0 + row) * 64 + chunk * 8] =
          *(const uint4*)&Ep[row * 72 + chunk * 8];
    }
  } else if (tile < 20) {
    // ---- K: rope -> rms -> Ep -> Kf fragment layout ----
    const int kv = tile - 16;
#pragma unroll
    for (int mt = 0; mt < 2; mt++) {
      float rvv[4][4];
#pragma unroll
      for (int ntp = 0; ntp < 2; ntp++) {
        int d31 = ntp * 16 + r0;
#pragma unroll
        for (int r = 0; r < 4; r++) {
          int s = s0 + w * 32 + mt * 16 + q * 4 + r;
          float c = cosb[s * 32 + d31], sn = sinb[s * 32 + d31];
          float v1 = acc[mt][ntp][r], v2 = acc[mt][ntp + 2][r];
          rvv[ntp][r] = v1 * c + v2 * sn;
          rvv[ntp + 2][r] = v2 * c - v1 * sn;
        }
      }
#pragma unroll
      for (int r = 0; r < 4; r++) {
        float ss = 0.f;
#pragma unroll
        for (int nt = 0; nt < 4; nt++) ss += rvv[nt][r] * rvv[nt][r];
        ss += __shfl_xor(ss, 1, 64);
        ss += __shfl_xor(ss, 2, 64);
        ss += __shfl_xor(ss, 4, 64);
        ss += __shfl_xor(ss, 8, 64);
        float sc = rsqrtf(ss * (1.f / 64.f) + EPS);
        int row = w * 32 + mt * 16 + q * 4 + r;
#pragma unroll
        for (int nt = 0; nt < 4; nt++)
          Ep[row * 72 + nt * 16 + r0] = (bf16)(rvv[nt][r] * sc);
      }
    }
    __syncthreads();
    // each wave extracts frags for its own 32-key sub-tile
    {
      int tk = (s0 >> 5) + w;
      size_t tb = ((size_t)(b * 4 + kv) * 64 + tk) * 2048;
#pragma unroll
      for (int u = 0; u < 4; u++) {
        int joff = (u >= 2) ? 16 : 0, doff = (u & 1) * 32;
        bf16x8 f = *(const bf16x8*)&Ep[(w * 32 + joff + r0) * 72 + doff + q * 8];
        *(bf16x8*)&Kf[tb + u * 512 + lane * 8] = f;
      }
    }
  } else {
    // ---- V: + gate*ve -> Ep -> Vf fragment layout ----
    const int kv = tile - 20;
    const float* gbase = gate + ((size_t)b * 4 + kv) * 2048;
#pragma unroll
    for (int mt = 0; mt < 2; mt++) {
#pragma unroll
      for (int r = 0; r < 4; r++) {
        int row = w * 32 + mt * 16 + q * 4 + r;
        float gg = gbase[s0 + row];
#pragma unroll
        for (int nt = 0; nt < 4; nt++) {
          int d = nt * 16 + r0;
          float vv = acc[mt][nt][r] + gg * ve[(size_t)(m0 + row) * 256 + kv * 64 + d];
          Ep[row * 72 + d] = (bf16)vv;
        }
      }
    }
    __syncthreads();
    {
      int tk = (s0 >> 5) + w;
      size_t tb = ((size_t)(b * 4 + kv) * 64 + tk) * 2048;
#pragma unroll
      for (int nt = 0; nt < 4; nt++) {
        bf16 tmp[8];
#pragma unroll
        for (int e = 0; e < 8; e++) {
          int jl = w * 32 + (e >> 2) * 16 + 4 * q + (e & 3);
          tmp[e] = Ep[jl * 72 + nt * 16 + r0];
        }
        *(uint4*)&Vf[tb + nt * 512 + lane * 8] = *(uint4*)tmp;
      }
    }
  }
}

// ---------------- proj GEMM: 128m x 64n, BK=64, fp32 out, XCD-chunked swizzle ------
__global__ __launch_bounds__(256) void proj_gemm_kernel(const bf16* __restrict__ A,
                                                        const bf16* __restrict__ Bt,
                                                        float* __restrict__ Cout) {
  __shared__ __align__(16) bf16 As[2 * 128 * 32];
  __shared__ __align__(16) bf16 Bs[2 * 64 * 32];
  const int K = 1024, N = 1024;
  const int tid = threadIdx.x;
  // XCD-chunked bijective swizzle (512 % 8 == 0): XCD k -> 4 consecutive m-panels
  const int orig = blockIdx.x;
  const int lid = (orig & 7) * 64 + (orig >> 3);
  const int m0 = (lid / 16) * 128, n0 = (lid % 16) * 64;
  const int w = tid >> 6, lane = tid & 63;
  const int q = lane >> 4, r0 = lane & 15;
  const int lrow = lane >> 2, lcol = (lane & 3) * 8;

  floatx4 acc[2][4];
#pragma unroll
  for (int i = 0; i < 2; i++)
#pragma unroll
    for (int j = 0; j < 4; j++) acc[i][j] = (floatx4){0.f, 0.f, 0.f, 0.f};

  for (int k0 = 0; k0 < K; k0 += 64) {
    __syncthreads();
#pragma unroll
    for (int i = 0; i < 4; i++) {
      int g = w * 4 + i, s = g >> 3, rb = g & 7;
      gload16(A + (size_t)(m0 + rb * 16 + lrow) * K + k0 + s * 32 + lcol, &As[s * 4096 + rb * 512]);
    }
#pragma unroll
    for (int i = 0; i < 2; i++) {
      int g = w * 2 + i, s = g >> 2, rb = g & 3;
      gload16(Bt + (size_t)(n0 + rb * 16 + lrow) * K + k0 + s * 32 + lcol, &Bs[s * 2048 + rb * 512]);
    }
    __syncthreads();
#pragma unroll
    for (int s = 0; s < 2; s++) {
      bf16x8 af[2], bfr[4];
#pragma unroll
      for (int mt = 0; mt < 2; mt++) af[mt] = *(const bf16x8*)&As[s * 4096 + (w * 32 + mt * 16 + r0) * 32 + q * 8];
#pragma unroll
      for (int nt = 0; nt < 4; nt++) bfr[nt] = *(const bf16x8*)&Bs[s * 2048 + (nt * 16 + r0) * 32 + q * 8];
#pragma unroll
      for (int mt = 0; mt < 2; mt++)
#pragma unroll
        for (int nt = 0; nt < 4; nt++)
          acc[mt][nt] = mfma16(af[mt], bfr[nt], acc[mt][nt]);
    }
  }
#pragma unroll
  for (int mt = 0; mt < 2; mt++)
#pragma unroll
    for (int nt = 0; nt < 4; nt++)
#pragma unroll
      for (int r = 0; r < 4; r++) {
        int row = m0 + w * 32 + mt * 16 + q * 4 + r;
        int col = n0 + nt * 16 + r0;
        Cout[(size_t)row * N + col] = acc[mt][nt][r];
      }
}

// ---------------- flash attention: LDS-shared K/V, 16 q/wave, 4096 waves (R6 best) ----
// R8 lesson: 32q/wave halved blocks/CU (4->2) and lost the multi-block stall
// coverage (+9us). This R6 form (4 blocks/CU) is the measured best (~29us).
__global__ __launch_bounds__(256, 4) void attn_kernel(const bf16* __restrict__ Qb,
                                                      const bf16* __restrict__ Kf,
                                                      const bf16* __restrict__ Vf,
                                                      const int* __restrict__ wlp,
                                                      const int* __restrict__ wrp,
                                                      bf16* __restrict__ Yb) {
  __shared__ __align__(16) bf16 Ks[2048];  // one 32-key tile, fragment order (4KB)
  __shared__ __align__(16) bf16 Vs[2048];  // 8KB/block, 4 blocks/CU
  const int wl = wlp[0];
  const int wrc = min(wrp[0], 0);  // j<=i+wr && j<=i  ==>  j <= i+min(wr,0)
  const int blk = blockIdx.x;
  const int bkv = blk & 7;  // XCD round-robin -> K/V L2-resident per XCD
  const int b = bkv >> 2, kvh = bkv & 3;
  const int cm = 127 - (blk >> 3);  // chunk of 16 queries, big windows first
  const int w = threadIdx.x >> 6, lane = threadIdx.x & 63;
  const int q = lane >> 4, r0 = lane & 15;
  const int h = kvh * 4 + w;
  const int q0 = cm << 4;

  const bf16* qbase = Qb + (((size_t)b * 16 + h) * 2048 + q0 + r0) * 64;
  bf16x8 aq0 = *(const bf16x8*)(qbase + q * 8);
  bf16x8 aq1 = *(const bf16x8*)(qbase + 32 + q * 8);

  floatx4 O[4];
#pragma unroll
  for (int nt = 0; nt < 4; nt++) O[nt] = (floatx4){0.f, 0.f, 0.f, 0.f};
  floatx4 L = (floatx4){0.f, 0.f, 0.f, 0.f};

  const bf16 onev = (bf16)1.0f;
  const bf16x8 ones = {onev, onev, onev, onev, onev, onev, onev, onev};

  // all 4 waves share cm -> identical jlo/count -> no barrier divergence
  const int jlo = max(0, q0 - wl) & ~31;
  const int jhi = q0 + 15 + wrc;
  const int count = ((jhi - jlo) >> 5) + 1;
  const int tile0 = jlo >> 5;

  const bf16* kfb = Kf + ((size_t)(b * 4 + kvh) * 64) * 2048;  // staging base (no lane offset)
  const bf16* vfb = Vf + ((size_t)(b * 4 + kvh) * 64) * 2048;

  for (int t = 0; t < count; t++) {
    const int j0 = jlo + (t << 5);
    const bf16* kt = kfb + (size_t)(tile0 + t) * 2048;
    const bf16* vt = vfb + (size_t)(tile0 + t) * 2048;
    __syncthreads();  // all waves done reading Ks/Vs of previous tile
    // stage tile: 8 chunks of 1KB (gload16 dest = base + lane*16). Wave w: chunks 2w, 2w+1.
#pragma unroll
    for (int i = 0; i < 2; i++) {
      int c = 2 * w + i;
      if (c < 4) gload16(kt + c * 512 + lane * 8, &Ks[c * 512]);
      else       gload16(vt + (c - 4) * 512 + lane * 8, &Vs[(c - 4) * 512]);
    }
    __syncthreads();  // implicit vmcnt(0)+lgkmcnt(0) drain: Ks/Vs valid

    bf16x8 kf0 = *(const bf16x8*)&Ks[0 * 512 + lane * 8];
    bf16x8 kf1 = *(const bf16x8*)&Ks[1 * 512 + lane * 8];
    bf16x8 kf2 = *(const bf16x8*)&Ks[2 * 512 + lane * 8];
    bf16x8 kf3 = *(const bf16x8*)&Ks[3 * 512 + lane * 8];

    // S = K·Q^T - SHIFT_C (C-layout: row j-j0 = 4q+r (+16 for s1), col query = r0)
    floatx4 s0 = (floatx4){-SHIFT_C, -SHIFT_C, -SHIFT_C, -SHIFT_C};
    floatx4 s1 = s0;
    __builtin_amdgcn_s_setprio(1);
    s0 = mfma16(kf0, aq0, s0);
    s0 = mfma16(kf1, aq1, s0);
    s1 = mfma16(kf2, aq0, s1);
    s1 = mfma16(kf3, aq1, s1);
    __builtin_amdgcn_s_setprio(0);

    bf16x8 pa;
    if (j0 >= q0 + 15 - wl && j0 + 31 <= q0 + wrc) {
      // tile fully inside window for all 16 queries
#pragma unroll
      for (int r = 0; r < 4; r++) {
        pa[r] = (bf16)exp2f(s0[r]);
        pa[4 + r] = (bf16)exp2f(s1[r]);
      }
    } else {
      const int i = q0 + r0;
#pragma unroll
      for (int r = 0; r < 4; r++) {
        int ja = j0 + 4 * q + r, jb = ja + 16;
        bool va = (ja <= i + wrc) && (ja >= i - wl);
        bool vb = (jb <= i + wrc) && (jb >= i - wl);
        pa[r] = va ? (bf16)exp2f(s0[r]) : (bf16)0.f;
        pa[4 + r] = vb ? (bf16)exp2f(s1[r]) : (bf16)0.f;
      }
    }

    bf16x8 vf0 = *(const bf16x8*)&Vs[0 * 512 + lane * 8];
    bf16x8 vf1 = *(const bf16x8*)&Vs[1 * 512 + lane * 8];
    bf16x8 vf2 = *(const bf16x8*)&Vs[2 * 512 + lane * 8];
    bf16x8 vf3 = *(const bf16x8*)&Vs[3 * 512 + lane * 8];

    __builtin_amdgcn_s_setprio(1);
    L = mfma16(pa, ones, L);
    O[0] = mfma16(pa, vf0, O[0]);
    O[1] = mfma16(pa, vf1, O[1]);
    O[2] = mfma16(pa, vf2, O[2]);
    O[3] = mfma16(pa, vf3, O[3]);
    __builtin_amdgcn_s_setprio(0);
  }

  // O/L C-layout: row i-q0 = q*4+r, col d = nt*16+r0
  float inv[4];
#pragma unroll
  for (int r = 0; r < 4; r++) inv[r] = 1.f / L[r];
#pragma unroll
  for (int nt = 0; nt < 4; nt++)
#pragma unroll
    for (int r = 0; r < 4; r++) {
      int i = q0 + q * 4 + r;
      Yb[((size_t)b * 2048 + i) * 1024 + h * 64 + nt * 16 + r0] = (bf16)(O[nt][r] * inv[r]);
    }
}

// ---------------- launch ----------------
// ATTRIBUTION PROBE: qkv_gemm and proj_gemm each launched TWICE (both idempotent:
// qkv reads Xb/gateb -> writes Qb/Kf/Vf; proj reads Yb -> writes d_out).
// dur_us minus R6's 163.3 baseline = qkv + proj combined duration S.
// Decision rule for next round: S >= 65 -> 128x128-tile GEMM rewrite (proj first:
// 256 blocks = exactly 1/CU); S in [45,65) -> proj-only rewrite; S < 45 -> the
// missing time is graph/launch overhead -> fuse kernels instead.
// attn is reverted to the R6 measured-best form (R8's 32q/wave cost +9us).
extern "C" void kernel_launch(void* const* d_in, const int* in_sizes, int n_in,
                              void* d_out, int out_size, void* d_ws, size_t ws_size,
                              hipStream_t stream) {
  const float* x     = (const float*)d_in[0];
  const float* ve    = (const float*)d_in[1];
  const float* cosb  = (const float*)d_in[2];
  const float* sinb  = (const float*)d_in[3];
  const float* Wq    = (const float*)d_in[4];
  const float* Wk    = (const float*)d_in[5];
  const float* Wv    = (const float*)d_in[6];
  const float* Wproj = (const float*)d_in[7];
  const float* Wgate = (const float*)d_in[8];
  const int* wl      = (const int*)d_in[9];
  const int* wr      = (const int*)d_in[10];

  char* ws = (char*)d_ws;
  bf16* Xb      = (bf16*)(ws);                 //  8,388,608 B: x bf16 [4096][1024]
  bf16* Wqkv_t  = (bf16*)(ws + 8388608);       //  3,145,728 B: [1536][1024]
  bf16* Wproj_t = (bf16*)(ws + 11534336);      //  2,097,152 B: [1024][1024]
  bf16* Qb      = (bf16*)(ws + 13631488);      //  8,388,608 B: [2][16][2048][64]
  bf16* Kf      = (bf16*)(ws + 22020096);      //  2,097,152 B: frag K [8][64 tiles][2048]
  bf16* Vf      = (bf16*)(ws + 24117248);      //  2,097,152 B: frag V
  bf16* Yb      = (bf16*)(ws + 26214400);      //  8,388,608 B: [4096][1024]
  float* gateb  = (float*)(ws + 34603008);     //     65,536 B: [2][4][2048]

  prep_kernel<<<4096 + 2560, 256, 0, stream>>>(x, Wgate, Wq, Wk, Wv, Wproj, Xb, gateb, Wqkv_t, Wproj_t);
  qkv_gemm_kernel<<<768, 256, 0, stream>>>(Xb, Wqkv_t, ve, cosb, sinb, gateb, Qb, Kf, Vf);
  qkv_gemm_kernel<<<768, 256, 0, stream>>>(Xb, Wqkv_t, ve, cosb, sinb, gateb, Qb, Kf, Vf);  // probe
  attn_kernel<<<1024, 256, 0, stream>>>(Qb, Kf, Vf, wl, wr, Yb);
  proj_gemm_kernel<<<512, 256, 0, stream>>>(Yb, Wproj_t, (float*)d_out);
  proj_gemm_kernel<<<512, 256, 0, stream>>>(Yb, Wproj_t, (float*)d_out);  // probe
}

// Round 10
// 167.139 us; speedup vs baseline: 1.1713x; 1.1713x over previous
//
#include <hip/hip_runtime.h>

typedef __bf16 bf16;
typedef __bf16 bf16x4 __attribute__((ext_vector_type(4)));
typedef __bf16 bf16x8 __attribute__((ext_vector_type(8)));
typedef float floatx4 __attribute__((ext_vector_type(4)));

#define EPS 1.1920929e-07f
// q scale = D^-0.5 * log2(e) folded together (D=64 -> 0.125)
#define QSCALE (0.125f * 1.44269504088896f)
// fixed softmax shift: |q_eff . k| <= ||q_eff||*||k|| = (8*QSCALE)*8 = 11.5416
#define SHIFT_C 11.5416f

__device__ __forceinline__ floatx4 mfma16(bf16x8 a, bf16x8 b, floatx4 c) {
  return __builtin_amdgcn_mfma_f32_16x16x32_bf16(a, b, c, 0, 0, 0);
}

// async 16B global->LDS: HW writes ldsbase + lane*16; gptr is per-lane
__device__ __forceinline__ void gload16(const void* g, void* l) {
  __builtin_amdgcn_global_load_lds((const __attribute__((address_space(1))) unsigned int*)g,
                                   (__attribute__((address_space(3))) unsigned int*)l, 16, 0, 0);
}

// ---------------- merged prep: cast+gate (blocks <4096) | weight pack (blocks >=4096) ----
__global__ void prep_kernel(const float* __restrict__ x, const float* __restrict__ wgate,
                            const float* __restrict__ Wq, const float* __restrict__ Wk,
                            const float* __restrict__ Wv, const float* __restrict__ Wproj,
                            bf16* __restrict__ xb, float* __restrict__ gate,
                            bf16* __restrict__ out_qkv, bf16* __restrict__ out_proj) {
  __shared__ float tile[32][33];
  const int tid = threadIdx.x;
  if (blockIdx.x < 4096) {
    // ---- cast + gate: one block per token ----
    int t = blockIdx.x;
    const float* xr = x + (size_t)t * 1024;
    float4 v = *(const float4*)(xr + tid * 4);
    bf16x4 o = {(bf16)v.x, (bf16)v.y, (bf16)v.z, (bf16)v.w};
    *(bf16x4*)(xb + (size_t)t * 1024 + tid * 4) = o;
    if (tid < 64) {
      int c = (tid & 31) * 4;  // gate columns come from lanes 0..31 only
#pragma unroll
      for (int kv = 0; kv < 4; kv++) {
        float g = v.x * wgate[(c + 0) * 4 + kv] + v.y * wgate[(c + 1) * 4 + kv] +
                  v.z * wgate[(c + 2) * 4 + kv] + v.w * wgate[(c + 3) * 4 + kv];
        g += __shfl_xor(g, 1, 64);
        g += __shfl_xor(g, 2, 64);
        g += __shfl_xor(g, 4, 64);
        g += __shfl_xor(g, 8, 64);
        g += __shfl_xor(g, 16, 64);
        if (tid == 0) {
          int b = t >> 11, s = t & 2047;
          gate[((size_t)b * 4 + kv) * 2048 + s] = 2.f / (1.f + __expf(-g));
        }
      }
    }
  } else {
    // ---- weight pack: qkv (nx<48) + wproj (nx>=48) ----
    int j = blockIdx.x - 4096;
    int ky = j / 80;
    int nx = j - ky * 80;
    int k0 = ky * 32;
    int tx = tid & 31, ty = tid >> 5;
    if (nx < 48) {
      int n0 = nx * 32;
#pragma unroll
      for (int i = 0; i < 4; i++) {
        int k = k0 + ty + i * 8, n = n0 + tx;
        float v;
        if (n < 1024)      v = Wq[(size_t)k * 1024 + n];
        else if (n < 1280) v = Wk[(size_t)k * 256 + (n - 1024)];
        else               v = Wv[(size_t)k * 256 + (n - 1280)];
        tile[ty + i * 8][tx] = v;
      }
      __syncthreads();
#pragma unroll
      for (int i = 0; i < 4; i++) {
        int n = n0 + ty + i * 8, k = k0 + tx;
        out_qkv[(size_t)n * 1024 + k] = (bf16)tile[tx][ty + i * 8];
      }
    } else {
      int n0 = (nx - 48) * 32;
#pragma unroll
      for (int i = 0; i < 4; i++)
        tile[ty + i * 8][tx] = Wproj[(size_t)(k0 + ty + i * 8) * 1024 + n0 + tx];
      __syncthreads();
#pragma unroll
      for (int i = 0; i < 4; i++)
        out_proj[(size_t)(n0 + ty + i * 8) * 1024 + k0 + tx] = (bf16)tile[tx][ty + i * 8];
    }
  }
}

// ---------------- fused QKV GEMM: 128m x 64n tiles, BK=64, + RoPE/RMS/gate epilogue ----
// R6 known-good form. Single-buffer, 2 barriers/K-step, 24KB LDS, 3 blocks/CU.
// Measured ~660 TF (R9 probe) = 75% of m97-structure ceiling -> left as-is.
__global__ __launch_bounds__(256) void qkv_gemm_kernel(const bf16* __restrict__ A,
                                                       const bf16* __restrict__ Bt,
                                                       const float* __restrict__ ve,
                                                       const float* __restrict__ cosb,
                                                       const float* __restrict__ sinb,
                                                       const float* __restrict__ gate,
                                                       bf16* __restrict__ Qb,
                                                       bf16* __restrict__ Kf,
                                                       bf16* __restrict__ Vf) {
  __shared__ __align__(16) char smem[24576];  // As 16K (2 halves x 128 x 32) + Bs 8K; epilogue Ep 128x72 bf16
  bf16* As = (bf16*)smem;
  bf16* Bs = (bf16*)(smem + 16384);
  bf16* Ep = (bf16*)smem;
  const int K = 1024;
  const int tid = threadIdx.x;
  // XCD-chunked bijective swizzle (768 % 8 == 0)
  const int orig = blockIdx.x;
  const int lid = (orig & 7) * 96 + (orig >> 3);
  const int tile = lid % 24;        // n-tile
  const int m0 = (lid / 24) * 128, n0 = tile * 64;
  const int w = tid >> 6, lane = tid & 63;
  const int q = lane >> 4, r0 = lane & 15;
  const int lrow = lane >> 2, lcol = (lane & 3) * 8;
  const int b = m0 >> 11, s0 = m0 & 2047;

  floatx4 acc[2][4];
#pragma unroll
  for (int i = 0; i < 2; i++)
#pragma unroll
    for (int j = 0; j < 4; j++) acc[i][j] = (floatx4){0.f, 0.f, 0.f, 0.f};

  for (int k0 = 0; k0 < K; k0 += 64) {
    __syncthreads();
    // A: 16 gloads (half s, row-block rb): wave w issues g = w*4..w*4+3
#pragma unroll
    for (int i = 0; i < 4; i++) {
      int g = w * 4 + i, s = g >> 3, rb = g & 7;
      gload16(A + (size_t)(m0 + rb * 16 + lrow) * K + k0 + s * 32 + lcol, &As[s * 4096 + rb * 512]);
    }
    // B: 8 gloads: wave w issues g = w*2, w*2+1
#pragma unroll
    for (int i = 0; i < 2; i++) {
      int g = w * 2 + i, s = g >> 2, rb = g & 3;
      gload16(Bt + (size_t)(n0 + rb * 16 + lrow) * K + k0 + s * 32 + lcol, &Bs[s * 2048 + rb * 512]);
    }
    __syncthreads();
#pragma unroll
    for (int s = 0; s < 2; s++) {
      bf16x8 af[2], bfr[4];
#pragma unroll
      for (int mt = 0; mt < 2; mt++) af[mt] = *(const bf16x8*)&As[s * 4096 + (w * 32 + mt * 16 + r0) * 32 + q * 8];
#pragma unroll
      for (int nt = 0; nt < 4; nt++) bfr[nt] = *(const bf16x8*)&Bs[s * 2048 + (nt * 16 + r0) * 32 + q * 8];
#pragma unroll
      for (int mt = 0; mt < 2; mt++)
#pragma unroll
        for (int nt = 0; nt < 4; nt++)
          acc[mt][nt] = mfma16(af[mt], bfr[nt], acc[mt][nt]);
    }
  }
  __syncthreads();  // all LDS reads done; Ep reuses the space

  // lane owns rows w*32 + mt*16 + q*4 + r (token - m0), d = nt*16 + r0
  if (tile < 16) {
    // ---- Q: rope -> rms -> *QSCALE -> Ep -> coalesced Qb copy ----
    const int h = tile;
#pragma unroll
    for (int mt = 0; mt < 2; mt++) {
      float rvv[4][4];
#pragma unroll
      for (int ntp = 0; ntp < 2; ntp++) {
        int d31 = ntp * 16 + r0;
#pragma unroll
        for (int r = 0; r < 4; r++) {
          int s = s0 + w * 32 + mt * 16 + q * 4 + r;
          float c = cosb[s * 32 + d31], sn = sinb[s * 32 + d31];
          float v1 = acc[mt][ntp][r], v2 = acc[mt][ntp + 2][r];
          rvv[ntp][r] = v1 * c + v2 * sn;
          rvv[ntp + 2][r] = v2 * c - v1 * sn;
        }
      }
#pragma unroll
      for (int r = 0; r < 4; r++) {
        float ss = 0.f;
#pragma unroll
        for (int nt = 0; nt < 4; nt++) ss += rvv[nt][r] * rvv[nt][r];
        ss += __shfl_xor(ss, 1, 64);
        ss += __shfl_xor(ss, 2, 64);
        ss += __shfl_xor(ss, 4, 64);
        ss += __shfl_xor(ss, 8, 64);
        float sc = rsqrtf(ss * (1.f / 64.f) + EPS) * QSCALE;
        int row = w * 32 + mt * 16 + q * 4 + r;
#pragma unroll
        for (int nt = 0; nt < 4; nt++)
          Ep[row * 72 + nt * 16 + r0] = (bf16)(rvv[nt][r] * sc);
      }
    }
    __syncthreads();
#pragma unroll
    for (int p = 0; p < 4; p++) {
      int g = p * 256 + tid;
      int row = g >> 3, chunk = g & 7;
      *(uint4*)&Qb[(((size_t)b * 16 + h) * 2048 + s0 + row) * 64 + chunk * 8] =
          *(const uint4*)&Ep[row * 72 + chunk * 8];
    }
  } else if (tile < 20) {
    // ---- K: rope -> rms -> Ep -> Kf fragment layout ----
    const int kv = tile - 16;
#pragma unroll
    for (int mt = 0; mt < 2; mt++) {
      float rvv[4][4];
#pragma unroll
      for (int ntp = 0; ntp < 2; ntp++) {
        int d31 = ntp * 16 + r0;
#pragma unroll
        for (int r = 0; r < 4; r++) {
          int s = s0 + w * 32 + mt * 16 + q * 4 + r;
          float c = cosb[s * 32 + d31], sn = sinb[s * 32 + d31];
          float v1 = acc[mt][ntp][r], v2 = acc[mt][ntp + 2][r];
          rvv[ntp][r] = v1 * c + v2 * sn;
          rvv[ntp + 2][r] = v2 * c - v1 * sn;
        }
      }
#pragma unroll
      for (int r = 0; r < 4; r++) {
        float ss = 0.f;
#pragma unroll
        for (int nt = 0; nt < 4; nt++) ss += rvv[nt][r] * rvv[nt][r];
        ss += __shfl_xor(ss, 1, 64);
        ss += __shfl_xor(ss, 2, 64);
        ss += __shfl_xor(ss, 4, 64);
        ss += __shfl_xor(ss, 8, 64);
        float sc = rsqrtf(ss * (1.f / 64.f) + EPS);
        int row = w * 32 + mt * 16 + q * 4 + r;
#pragma unroll
        for (int nt = 0; nt < 4; nt++)
          Ep[row * 72 + nt * 16 + r0] = (bf16)(rvv[nt][r] * sc);
      }
    }
    __syncthreads();
    // each wave extracts frags for its own 32-key sub-tile
    {
      int tk = (s0 >> 5) + w;
      size_t tb = ((size_t)(b * 4 + kv) * 64 + tk) * 2048;
#pragma unroll
      for (int u = 0; u < 4; u++) {
        int joff = (u >= 2) ? 16 : 0, doff = (u & 1) * 32;
        bf16x8 f = *(const bf16x8*)&Ep[(w * 32 + joff + r0) * 72 + doff + q * 8];
        *(bf16x8*)&Kf[tb + u * 512 + lane * 8] = f;
      }
    }
  } else {
    // ---- V: + gate*ve -> Ep -> Vf fragment layout ----
    const int kv = tile - 20;
    const float* gbase = gate + ((size_t)b * 4 + kv) * 2048;
#pragma unroll
    for (int mt = 0; mt < 2; mt++) {
#pragma unroll
      for (int r = 0; r < 4; r++) {
        int row = w * 32 + mt * 16 + q * 4 + r;
        float gg = gbase[s0 + row];
#pragma unroll
        for (int nt = 0; nt < 4; nt++) {
          int d = nt * 16 + r0;
          float vv = acc[mt][nt][r] + gg * ve[(size_t)(m0 + row) * 256 + kv * 64 + d];
          Ep[row * 72 + d] = (bf16)vv;
        }
      }
    }
    __syncthreads();
    {
      int tk = (s0 >> 5) + w;
      size_t tb = ((size_t)(b * 4 + kv) * 64 + tk) * 2048;
#pragma unroll
      for (int nt = 0; nt < 4; nt++) {
        bf16 tmp[8];
#pragma unroll
        for (int e = 0; e < 8; e++) {
          int jl = w * 32 + (e >> 2) * 16 + 4 * q + (e & 3);
          tmp[e] = Ep[jl * 72 + nt * 16 + r0];
        }
        *(uint4*)&Vf[tb + nt * 512 + lane * 8] = *(uint4*)tmp;
      }
    }
  }
}

// ---------------- proj GEMM: 128m x 64n, BK=64, fp32 out, XCD-chunked swizzle ------
// Measured ~660 TF (R9 probe) -> left as-is.
__global__ __launch_bounds__(256) void proj_gemm_kernel(const bf16* __restrict__ A,
                                                        const bf16* __restrict__ Bt,
                                                        float* __restrict__ Cout) {
  __shared__ __align__(16) bf16 As[2 * 128 * 32];
  __shared__ __align__(16) bf16 Bs[2 * 64 * 32];
  const int K = 1024, N = 1024;
  const int tid = threadIdx.x;
  // XCD-chunked bijective swizzle (512 % 8 == 0): XCD k -> 4 consecutive m-panels
  const int orig = blockIdx.x;
  const int lid = (orig & 7) * 64 + (orig >> 3);
  const int m0 = (lid / 16) * 128, n0 = (lid % 16) * 64;
  const int w = tid >> 6, lane = tid & 63;
  const int q = lane >> 4, r0 = lane & 15;
  const int lrow = lane >> 2, lcol = (lane & 3) * 8;

  floatx4 acc[2][4];
#pragma unroll
  for (int i = 0; i < 2; i++)
#pragma unroll
    for (int j = 0; j < 4; j++) acc[i][j] = (floatx4){0.f, 0.f, 0.f, 0.f};

  for (int k0 = 0; k0 < K; k0 += 64) {
    __syncthreads();
#pragma unroll
    for (int i = 0; i < 4; i++) {
      int g = w * 4 + i, s = g >> 3, rb = g & 7;
      gload16(A + (size_t)(m0 + rb * 16 + lrow) * K + k0 + s * 32 + lcol, &As[s * 4096 + rb * 512]);
    }
#pragma unroll
    for (int i = 0; i < 2; i++) {
      int g = w * 2 + i, s = g >> 2, rb = g & 3;
      gload16(Bt + (size_t)(n0 + rb * 16 + lrow) * K + k0 + s * 32 + lcol, &Bs[s * 2048 + rb * 512]);
    }
    __syncthreads();
#pragma unroll
    for (int s = 0; s < 2; s++) {
      bf16x8 af[2], bfr[4];
#pragma unroll
      for (int mt = 0; mt < 2; mt++) af[mt] = *(const bf16x8*)&As[s * 4096 + (w * 32 + mt * 16 + r0) * 32 + q * 8];
#pragma unroll
      for (int nt = 0; nt < 4; nt++) bfr[nt] = *(const bf16x8*)&Bs[s * 2048 + (nt * 16 + r0) * 32 + q * 8];
#pragma unroll
      for (int mt = 0; mt < 2; mt++)
#pragma unroll
        for (int nt = 0; nt < 4; nt++)
          acc[mt][nt] = mfma16(af[mt], bfr[nt], acc[mt][nt]);
    }
  }
#pragma unroll
  for (int mt = 0; mt < 2; mt++)
#pragma unroll
    for (int nt = 0; nt < 4; nt++)
#pragma unroll
      for (int r = 0; r < 4; r++) {
        int row = m0 + w * 32 + mt * 16 + q * 4 + r;
        int col = n0 + nt * 16 + r0;
        Cout[(size_t)row * N + col] = acc[mt][nt][r];
      }
}

// ---------------- flash attention: LDS-shared K/V, 4-tile staging batches --------
// R9 ledger: attn ~29us is the largest reducible term; pipes sum to ~12us, so the
// per-tile structure cost (26x {2 barriers + full vmcnt drain} per block, only 9
// MFMA/tile) dominates. Fix: stage FOUR 32-key K/V tiles per phase -> drain/barrier
// pairs 26 -> 7 at IDENTICAL occupancy (32KB LDS x 4 blocks/CU = 128 <= 160KB;
// blocks/CU is wave-limited at (256,4), unchanged). R7's regression was paying for
// amortization with blocks/CU; this pays with idle LDS instead. Same proven
// stage -> barrier -> compute -> barrier skeleton; staged bytes/MFMA/exp unchanged.
__global__ __launch_bounds__(256, 4) void attn_kernel(const bf16* __restrict__ Qb,
                                                      const bf16* __restrict__ Kf,
                                                      const bf16* __restrict__ Vf,
                                                      const int* __restrict__ wlp,
                                                      const int* __restrict__ wrp,
                                                      bf16* __restrict__ Yb) {
  __shared__ __align__(16) bf16 Ks[4 * 2048];  // up to 4 staged 32-key tiles (16KB)
  __shared__ __align__(16) bf16 Vs[4 * 2048];  // (16KB) -> 32KB/block
  const int wl = wlp[0];
  const int wrc = min(wrp[0], 0);  // j<=i+wr && j<=i  ==>  j <= i+min(wr,0)
  const int blk = blockIdx.x;
  const int bkv = blk & 7;  // XCD round-robin -> K/V L2-resident per XCD
  const int b = bkv >> 2, kvh = bkv & 3;
  const int cm = 127 - (blk >> 3);  // chunk of 16 queries, big windows first
  const int w = threadIdx.x >> 6, lane = threadIdx.x & 63;
  const int q = lane >> 4, r0 = lane & 15;
  const int h = kvh * 4 + w;
  const int q0 = cm << 4;

  const bf16* qbase = Qb + (((size_t)b * 16 + h) * 2048 + q0 + r0) * 64;
  bf16x8 aq0 = *(const bf16x8*)(qbase + q * 8);
  bf16x8 aq1 = *(const bf16x8*)(qbase + 32 + q * 8);

  floatx4 O[4];
#pragma unroll
  for (int nt = 0; nt < 4; nt++) O[nt] = (floatx4){0.f, 0.f, 0.f, 0.f};
  floatx4 L = (floatx4){0.f, 0.f, 0.f, 0.f};

  const bf16 onev = (bf16)1.0f;
  const bf16x8 ones = {onev, onev, onev, onev, onev, onev, onev, onev};

  // all 4 waves share cm -> identical jlo/count -> no barrier divergence
  const int jlo = max(0, q0 - wl) & ~31;
  const int jhi = q0 + 15 + wrc;
  const int count = ((jhi - jlo) >> 5) + 1;
  const int tile0 = jlo >> 5;

  const bf16* kfb = Kf + ((size_t)(b * 4 + kvh) * 64) * 2048;  // staging base (no lane offset)
  const bf16* vfb = Vf + ((size_t)(b * 4 + kvh) * 64) * 2048;

  for (int t = 0; t < count;) {
    const int ns = min(4, count - t);  // block-uniform (count shared by all waves)
    __syncthreads();  // all waves done reading previous batch
    // stage ns tiles: ns*8 chunks of 1KB, round-robin over waves (stride 4).
    // chunk c: tile u = c>>3, rem = c&7 (rem<4 -> K quarter, else V quarter).
    for (int c = w; c < ns * 8; c += 4) {
      int u = c >> 3, rem = c & 7;
      if (rem < 4)
        gload16(kfb + (size_t)(tile0 + t + u) * 2048 + rem * 512 + lane * 8,
                &Ks[u * 2048 + rem * 512]);
      else
        gload16(vfb + (size_t)(tile0 + t + u) * 2048 + (rem - 4) * 512 + lane * 8,
                &Vs[u * 2048 + (rem - 4) * 512]);
    }
    __syncthreads();  // implicit vmcnt(0)+lgkmcnt(0) drain: batch valid

    for (int u = 0; u < ns; u++) {
      const int j0 = jlo + ((t + u) << 5);
      const bf16* Ku = &Ks[u * 2048];
      const bf16* Vu = &Vs[u * 2048];

      bf16x8 kf0 = *(const bf16x8*)&Ku[0 * 512 + lane * 8];
      bf16x8 kf1 = *(const bf16x8*)&Ku[1 * 512 + lane * 8];
      bf16x8 kf2 = *(const bf16x8*)&Ku[2 * 512 + lane * 8];
      bf16x8 kf3 = *(const bf16x8*)&Ku[3 * 512 + lane * 8];

      // S = K·Q^T - SHIFT_C (C-layout: row j-j0 = 4q+r (+16 for s1), col query = r0)
      floatx4 s0 = (floatx4){-SHIFT_C, -SHIFT_C, -SHIFT_C, -SHIFT_C};
      floatx4 s1 = s0;
      __builtin_amdgcn_s_setprio(1);
      s0 = mfma16(kf0, aq0, s0);
      s0 = mfma16(kf1, aq1, s0);
      s1 = mfma16(kf2, aq0, s1);
      s1 = mfma16(kf3, aq1, s1);
      __builtin_amdgcn_s_setprio(0);

      bf16x8 pa;
      if (j0 >= q0 + 15 - wl && j0 + 31 <= q0 + wrc) {
        // tile fully inside window for all 16 queries
#pragma unroll
        for (int r = 0; r < 4; r++) {
          pa[r] = (bf16)exp2f(s0[r]);
          pa[4 + r] = (bf16)exp2f(s1[r]);
        }
      } else {
        const int i = q0 + r0;
#pragma unroll
        for (int r = 0; r < 4; r++) {
          int ja = j0 + 4 * q + r, jb = ja + 16;
          bool va = (ja <= i + wrc) && (ja >= i - wl);
          bool vb = (jb <= i + wrc) && (jb >= i - wl);
          pa[r] = va ? (bf16)exp2f(s0[r]) : (bf16)0.f;
          pa[4 + r] = vb ? (bf16)exp2f(s1[r]) : (bf16)0.f;
        }
      }

      bf16x8 vf0 = *(const bf16x8*)&Vu[0 * 512 + lane * 8];
      bf16x8 vf1 = *(const bf16x8*)&Vu[1 * 512 + lane * 8];
      bf16x8 vf2 = *(const bf16x8*)&Vu[2 * 512 + lane * 8];
      bf16x8 vf3 = *(const bf16x8*)&Vu[3 * 512 + lane * 8];

      __builtin_amdgcn_s_setprio(1);
      L = mfma16(pa, ones, L);
      O[0] = mfma16(pa, vf0, O[0]);
      O[1] = mfma16(pa, vf1, O[1]);
      O[2] = mfma16(pa, vf2, O[2]);
      O[3] = mfma16(pa, vf3, O[3]);
      __builtin_amdgcn_s_setprio(0);
    }
    t += ns;
  }

  // O/L C-layout: row i-q0 = q*4+r, col d = nt*16+r0
  float inv[4];
#pragma unroll
  for (int r = 0; r < 4; r++) inv[r] = 1.f / L[r];
#pragma unroll
  for (int nt = 0; nt < 4; nt++)
#pragma unroll
    for (int r = 0; r < 4; r++) {
      int i = q0 + q * 4 + r;
      Yb[((size_t)b * 2048 + i) * 1024 + h * 64 + nt * 16 + r0] = (bf16)(O[nt][r] * inv[r]);
    }
}

// ---------------- launch ----------------
extern "C" void kernel_launch(void* const* d_in, const int* in_sizes, int n_in,
                              void* d_out, int out_size, void* d_ws, size_t ws_size,
                              hipStream_t stream) {
  const float* x     = (const float*)d_in[0];
  const float* ve    = (const float*)d_in[1];
  const float* cosb  = (const float*)d_in[2];
  const float* sinb  = (const float*)d_in[3];
  const float* Wq    = (const float*)d_in[4];
  const float* Wk    = (const float*)d_in[5];
  const float* Wv    = (const float*)d_in[6];
  const float* Wproj = (const float*)d_in[7];
  const float* Wgate = (const float*)d_in[8];
  const int* wl      = (const int*)d_in[9];
  const int* wr      = (const int*)d_in[10];

  char* ws = (char*)d_ws;
  bf16* Xb      = (bf16*)(ws);                 //  8,388,608 B: x bf16 [4096][1024]
  bf16* Wqkv_t  = (bf16*)(ws + 8388608);       //  3,145,728 B: [1536][1024]
  bf16* Wproj_t = (bf16*)(ws + 11534336);      //  2,097,152 B: [1024][1024]
  bf16* Qb      = (bf16*)(ws + 13631488);      //  8,388,608 B: [2][16][2048][64]
  bf16* Kf      = (bf16*)(ws + 22020096);      //  2,097,152 B: frag K [8][64 tiles][2048]
  bf16* Vf      = (bf16*)(ws + 24117248);      //  2,097,152 B: frag V
  bf16* Yb      = (bf16*)(ws + 26214400);      //  8,388,608 B: [4096][1024]
  float* gateb  = (float*)(ws + 34603008);     //     65,536 B: [2][4][2048]

  prep_kernel<<<4096 + 2560, 256, 0, stream>>>(x, Wgate, Wq, Wk, Wv, Wproj, Xb, gateb, Wqkv_t, Wproj_t);
  qkv_gemm_kernel<<<768, 256, 0, stream>>>(Xb, Wqkv_t, ve, cosb, sinb, gateb, Qb, Kf, Vf);
  attn_kernel<<<1024, 256, 0, stream>>>(Qb, Kf, Vf, wl, wr, Yb);
  proj_gemm_kernel<<<512, 256, 0, stream>>>(Yb, Wproj_t, (float*)d_out);
}

// Round 11
// 160.442 us; speedup vs baseline: 1.2202x; 1.0417x over previous
//
#include <hip/hip_runtime.h>

typedef __bf16 bf16;
typedef __bf16 bf16x4 __attribute__((ext_vector_type(4)));
typedef __bf16 bf16x8 __attribute__((ext_vector_type(8)));
typedef float floatx4 __attribute__((ext_vector_type(4)));

#define EPS 1.1920929e-07f
// q scale = D^-0.5 * log2(e) folded together (D=64 -> 0.125)
#define QSCALE (0.125f * 1.44269504088896f)
// fixed softmax shift: |q_eff . k| <= ||q_eff||*||k|| = (8*QSCALE)*8 = 11.5416
#define SHIFT_C 11.5416f

__device__ __forceinline__ floatx4 mfma16(bf16x8 a, bf16x8 b, floatx4 c) {
  return __builtin_amdgcn_mfma_f32_16x16x32_bf16(a, b, c, 0, 0, 0);
}

// async 16B global->LDS: HW writes ldsbase + lane*16; gptr is per-lane
__device__ __forceinline__ void gload16(const void* g, void* l) {
  __builtin_amdgcn_global_load_lds((const __attribute__((address_space(1))) unsigned int*)g,
                                   (__attribute__((address_space(3))) unsigned int*)l, 16, 0, 0);
}

// ---------------- merged prep: cast+gate (blocks <4096) | weight pack (blocks >=4096) ----
__global__ void prep_kernel(const float* __restrict__ x, const float* __restrict__ wgate,
                            const float* __restrict__ Wq, const float* __restrict__ Wk,
                            const float* __restrict__ Wv, const float* __restrict__ Wproj,
                            bf16* __restrict__ xb, float* __restrict__ gate,
                            bf16* __restrict__ out_qkv, bf16* __restrict__ out_proj) {
  __shared__ float tile[32][33];
  const int tid = threadIdx.x;
  if (blockIdx.x < 4096) {
    // ---- cast + gate: one block per token ----
    int t = blockIdx.x;
    const float* xr = x + (size_t)t * 1024;
    float4 v = *(const float4*)(xr + tid * 4);
    bf16x4 o = {(bf16)v.x, (bf16)v.y, (bf16)v.z, (bf16)v.w};
    *(bf16x4*)(xb + (size_t)t * 1024 + tid * 4) = o;
    if (tid < 64) {
      int c = (tid & 31) * 4;  // gate columns come from lanes 0..31 only
#pragma unroll
      for (int kv = 0; kv < 4; kv++) {
        float g = v.x * wgate[(c + 0) * 4 + kv] + v.y * wgate[(c + 1) * 4 + kv] +
                  v.z * wgate[(c + 2) * 4 + kv] + v.w * wgate[(c + 3) * 4 + kv];
        g += __shfl_xor(g, 1, 64);
        g += __shfl_xor(g, 2, 64);
        g += __shfl_xor(g, 4, 64);
        g += __shfl_xor(g, 8, 64);
        g += __shfl_xor(g, 16, 64);
        if (tid == 0) {
          int b = t >> 11, s = t & 2047;
          gate[((size_t)b * 4 + kv) * 2048 + s] = 2.f / (1.f + __expf(-g));
        }
      }
    }
  } else {
    // ---- weight pack: qkv (nx<48) + wproj (nx>=48) ----
    int j = blockIdx.x - 4096;
    int ky = j / 80;
    int nx = j - ky * 80;
    int k0 = ky * 32;
    int tx = tid & 31, ty = tid >> 5;
    if (nx < 48) {
      int n0 = nx * 32;
#pragma unroll
      for (int i = 0; i < 4; i++) {
        int k = k0 + ty + i * 8, n = n0 + tx;
        float v;
        if (n < 1024)      v = Wq[(size_t)k * 1024 + n];
        else if (n < 1280) v = Wk[(size_t)k * 256 + (n - 1024)];
        else               v = Wv[(size_t)k * 256 + (n - 1280)];
        tile[ty + i * 8][tx] = v;
      }
      __syncthreads();
#pragma unroll
      for (int i = 0; i < 4; i++) {
        int n = n0 + ty + i * 8, k = k0 + tx;
        out_qkv[(size_t)n * 1024 + k] = (bf16)tile[tx][ty + i * 8];
      }
    } else {
      int n0 = (nx - 48) * 32;
#pragma unroll
      for (int i = 0; i < 4; i++)
        tile[ty + i * 8][tx] = Wproj[(size_t)(k0 + ty + i * 8) * 1024 + n0 + tx];
      __syncthreads();
#pragma unroll
      for (int i = 0; i < 4; i++)
        out_proj[(size_t)(n0 + ty + i * 8) * 1024 + k0 + tx] = (bf16)tile[tx][ty + i * 8];
    }
  }
}

// ---------------- fused QKV GEMM: 128m x 64n tiles, BK=64, + RoPE/RMS/gate epilogue ----
// R6 known-good form. Single-buffer, 2 barriers/K-step, 24KB LDS, 3 blocks/CU.
// Measured ~660 TF (R9 probe) = 75% of m97-structure ceiling -> left as-is.
__global__ __launch_bounds__(256) void qkv_gemm_kernel(const bf16* __restrict__ A,
                                                       const bf16* __restrict__ Bt,
                                                       const float* __restrict__ ve,
                                                       const float* __restrict__ cosb,
                                                       const float* __restrict__ sinb,
                                                       const float* __restrict__ gate,
                                                       bf16* __restrict__ Qb,
                                                       bf16* __restrict__ Kf,
                                                       bf16* __restrict__ Vf) {
  __shared__ __align__(16) char smem[24576];  // As 16K (2 halves x 128 x 32) + Bs 8K; epilogue Ep 128x72 bf16
  bf16* As = (bf16*)smem;
  bf16* Bs = (bf16*)(smem + 16384);
  bf16* Ep = (bf16*)smem;
  const int K = 1024;
  const int tid = threadIdx.x;
  // XCD-chunked bijective swizzle (768 % 8 == 0)
  const int orig = blockIdx.x;
  const int lid = (orig & 7) * 96 + (orig >> 3);
  const int tile = lid % 24;        // n-tile
  const int m0 = (lid / 24) * 128, n0 = tile * 64;
  const int w = tid >> 6, lane = tid & 63;
  const int q = lane >> 4, r0 = lane & 15;
  const int lrow = lane >> 2, lcol = (lane & 3) * 8;
  const int b = m0 >> 11, s0 = m0 & 2047;

  floatx4 acc[2][4];
#pragma unroll
  for (int i = 0; i < 2; i++)
#pragma unroll
    for (int j = 0; j < 4; j++) acc[i][j] = (floatx4){0.f, 0.f, 0.f, 0.f};

  for (int k0 = 0; k0 < K; k0 += 64) {
    __syncthreads();
    // A: 16 gloads (half s, row-block rb): wave w issues g = w*4..w*4+3
#pragma unroll
    for (int i = 0; i < 4; i++) {
      int g = w * 4 + i, s = g >> 3, rb = g & 7;
      gload16(A + (size_t)(m0 + rb * 16 + lrow) * K + k0 + s * 32 + lcol, &As[s * 4096 + rb * 512]);
    }
    // B: 8 gloads: wave w issues g = w*2, w*2+1
#pragma unroll
    for (int i = 0; i < 2; i++) {
      int g = w * 2 + i, s = g >> 2, rb = g & 3;
      gload16(Bt + (size_t)(n0 + rb * 16 + lrow) * K + k0 + s * 32 + lcol, &Bs[s * 2048 + rb * 512]);
    }
    __syncthreads();
#pragma unroll
    for (int s = 0; s < 2; s++) {
      bf16x8 af[2], bfr[4];
#pragma unroll
      for (int mt = 0; mt < 2; mt++) af[mt] = *(const bf16x8*)&As[s * 4096 + (w * 32 + mt * 16 + r0) * 32 + q * 8];
#pragma unroll
      for (int nt = 0; nt < 4; nt++) bfr[nt] = *(const bf16x8*)&Bs[s * 2048 + (nt * 16 + r0) * 32 + q * 8];
#pragma unroll
      for (int mt = 0; mt < 2; mt++)
#pragma unroll
        for (int nt = 0; nt < 4; nt++)
          acc[mt][nt] = mfma16(af[mt], bfr[nt], acc[mt][nt]);
    }
  }
  __syncthreads();  // all LDS reads done; Ep reuses the space

  // lane owns rows w*32 + mt*16 + q*4 + r (token - m0), d = nt*16 + r0
  if (tile < 16) {
    // ---- Q: rope -> rms -> *QSCALE -> Ep -> coalesced Qb copy ----
    const int h = tile;
#pragma unroll
    for (int mt = 0; mt < 2; mt++) {
      float rvv[4][4];
#pragma unroll
      for (int ntp = 0; ntp < 2; ntp++) {
        int d31 = ntp * 16 + r0;
#pragma unroll
        for (int r = 0; r < 4; r++) {
          int s = s0 + w * 32 + mt * 16 + q * 4 + r;
          float c = cosb[s * 32 + d31], sn = sinb[s * 32 + d31];
          float v1 = acc[mt][ntp][r], v2 = acc[mt][ntp + 2][r];
          rvv[ntp][r] = v1 * c + v2 * sn;
          rvv[ntp + 2][r] = v2 * c - v1 * sn;
        }
      }
#pragma unroll
      for (int r = 0; r < 4; r++) {
        float ss = 0.f;
#pragma unroll
        for (int nt = 0; nt < 4; nt++) ss += rvv[nt][r] * rvv[nt][r];
        ss += __shfl_xor(ss, 1, 64);
        ss += __shfl_xor(ss, 2, 64);
        ss += __shfl_xor(ss, 4, 64);
        ss += __shfl_xor(ss, 8, 64);
        float sc = rsqrtf(ss * (1.f / 64.f) + EPS) * QSCALE;
        int row = w * 32 + mt * 16 + q * 4 + r;
#pragma unroll
        for (int nt = 0; nt < 4; nt++)
          Ep[row * 72 + nt * 16 + r0] = (bf16)(rvv[nt][r] * sc);
      }
    }
    __syncthreads();
#pragma unroll
    for (int p = 0; p < 4; p++) {
      int g = p * 256 + tid;
      int row = g >> 3, chunk = g & 7;
      *(uint4*)&Qb[(((size_t)b * 16 + h) * 2048 + s0 + row) * 64 + chunk * 8] =
          *(const uint4*)&Ep[row * 72 + chunk * 8];
    }
  } else if (tile < 20) {
    // ---- K: rope -> rms -> Ep -> Kf fragment layout ----
    const int kv = tile - 16;
#pragma unroll
    for (int mt = 0; mt < 2; mt++) {
      float rvv[4][4];
#pragma unroll
      for (int ntp = 0; ntp < 2; ntp++) {
        int d31 = ntp * 16 + r0;
#pragma unroll
        for (int r = 0; r < 4; r++) {
          int s = s0 + w * 32 + mt * 16 + q * 4 + r;
          float c = cosb[s * 32 + d31], sn = sinb[s * 32 + d31];
          float v1 = acc[mt][ntp][r], v2 = acc[mt][ntp + 2][r];
          rvv[ntp][r] = v1 * c + v2 * sn;
          rvv[ntp + 2][r] = v2 * c - v1 * sn;
        }
      }
#pragma unroll
      for (int r = 0; r < 4; r++) {
        float ss = 0.f;
#pragma unroll
        for (int nt = 0; nt < 4; nt++) ss += rvv[nt][r] * rvv[nt][r];
        ss += __shfl_xor(ss, 1, 64);
        ss += __shfl_xor(ss, 2, 64);
        ss += __shfl_xor(ss, 4, 64);
        ss += __shfl_xor(ss, 8, 64);
        float sc = rsqrtf(ss * (1.f / 64.f) + EPS);
        int row = w * 32 + mt * 16 + q * 4 + r;
#pragma unroll
        for (int nt = 0; nt < 4; nt++)
          Ep[row * 72 + nt * 16 + r0] = (bf16)(rvv[nt][r] * sc);
      }
    }
    __syncthreads();
    // each wave extracts frags for its own 32-key sub-tile
    {
      int tk = (s0 >> 5) + w;
      size_t tb = ((size_t)(b * 4 + kv) * 64 + tk) * 2048;
#pragma unroll
      for (int u = 0; u < 4; u++) {
        int joff = (u >= 2) ? 16 : 0, doff = (u & 1) * 32;
        bf16x8 f = *(const bf16x8*)&Ep[(w * 32 + joff + r0) * 72 + doff + q * 8];
        *(bf16x8*)&Kf[tb + u * 512 + lane * 8] = f;
      }
    }
  } else {
    // ---- V: + gate*ve -> Ep -> Vf fragment layout ----
    const int kv = tile - 20;
    const float* gbase = gate + ((size_t)b * 4 + kv) * 2048;
#pragma unroll
    for (int mt = 0; mt < 2; mt++) {
#pragma unroll
      for (int r = 0; r < 4; r++) {
        int row = w * 32 + mt * 16 + q * 4 + r;
        float gg = gbase[s0 + row];
#pragma unroll
        for (int nt = 0; nt < 4; nt++) {
          int d = nt * 16 + r0;
          float vv = acc[mt][nt][r] + gg * ve[(size_t)(m0 + row) * 256 + kv * 64 + d];
          Ep[row * 72 + d] = (bf16)vv;
        }
      }
    }
    __syncthreads();
    {
      int tk = (s0 >> 5) + w;
      size_t tb = ((size_t)(b * 4 + kv) * 64 + tk) * 2048;
#pragma unroll
      for (int nt = 0; nt < 4; nt++) {
        bf16 tmp[8];
#pragma unroll
        for (int e = 0; e < 8; e++) {
          int jl = w * 32 + (e >> 2) * 16 + 4 * q + (e & 3);
          tmp[e] = Ep[jl * 72 + nt * 16 + r0];
        }
        *(uint4*)&Vf[tb + nt * 512 + lane * 8] = *(uint4*)tmp;
      }
    }
  }
}

// ---------------- proj GEMM: 128m x 64n, BK=64, fp32 out, XCD-chunked swizzle ------
// Measured ~660 TF (R9 probe) -> left as-is.
__global__ __launch_bounds__(256) void proj_gemm_kernel(const bf16* __restrict__ A,
                                                        const bf16* __restrict__ Bt,
                                                        float* __restrict__ Cout) {
  __shared__ __align__(16) bf16 As[2 * 128 * 32];
  __shared__ __align__(16) bf16 Bs[2 * 64 * 32];
  const int K = 1024, N = 1024;
  const int tid = threadIdx.x;
  // XCD-chunked bijective swizzle (512 % 8 == 0): XCD k -> 4 consecutive m-panels
  const int orig = blockIdx.x;
  const int lid = (orig & 7) * 64 + (orig >> 3);
  const int m0 = (lid / 16) * 128, n0 = (lid % 16) * 64;
  const int w = tid >> 6, lane = tid & 63;
  const int q = lane >> 4, r0 = lane & 15;
  const int lrow = lane >> 2, lcol = (lane & 3) * 8;

  floatx4 acc[2][4];
#pragma unroll
  for (int i = 0; i < 2; i++)
#pragma unroll
    for (int j = 0; j < 4; j++) acc[i][j] = (floatx4){0.f, 0.f, 0.f, 0.f};

  for (int k0 = 0; k0 < K; k0 += 64) {
    __syncthreads();
#pragma unroll
    for (int i = 0; i < 4; i++) {
      int g = w * 4 + i, s = g >> 3, rb = g & 7;
      gload16(A + (size_t)(m0 + rb * 16 + lrow) * K + k0 + s * 32 + lcol, &As[s * 4096 + rb * 512]);
    }
#pragma unroll
    for (int i = 0; i < 2; i++) {
      int g = w * 2 + i, s = g >> 2, rb = g & 3;
      gload16(Bt + (size_t)(n0 + rb * 16 + lrow) * K + k0 + s * 32 + lcol, &Bs[s * 2048 + rb * 512]);
    }
    __syncthreads();
#pragma unroll
    for (int s = 0; s < 2; s++) {
      bf16x8 af[2], bfr[4];
#pragma unroll
      for (int mt = 0; mt < 2; mt++) af[mt] = *(const bf16x8*)&As[s * 4096 + (w * 32 + mt * 16 + r0) * 32 + q * 8];
#pragma unroll
      for (int nt = 0; nt < 4; nt++) bfr[nt] = *(const bf16x8*)&Bs[s * 2048 + (nt * 16 + r0) * 32 + q * 8];
#pragma unroll
      for (int mt = 0; mt < 2; mt++)
#pragma unroll
        for (int nt = 0; nt < 4; nt++)
          acc[mt][nt] = mfma16(af[mt], bfr[nt], acc[mt][nt]);
    }
  }
#pragma unroll
  for (int mt = 0; mt < 2; mt++)
#pragma unroll
    for (int nt = 0; nt < 4; nt++)
#pragma unroll
      for (int r = 0; r < 4; r++) {
        int row = m0 + w * 32 + mt * 16 + q * 4 + r;
        int col = n0 + nt * 16 + r0;
        Cout[(size_t)row * N + col] = acc[mt][nt][r];
      }
}

// ---------------- flash attention: T14 async-STAGE split, double-buffered LDS ------
// R10 lesson: batching barriers didn't help -> the cost is the EXPOSED per-tile
// vmcnt(0) drain, not the barrier count. T14 (catalog: +17% on attn): issue next
// tile's K/V loads to REGISTERS before compute (1 uint4 K + 1 uint4 V per thread),
// consume them as ds_writes AFTER compute -> HBM/L2 latency hides under MFMA+exp.
// Cross-barrier loads go to REGS (plain global loads, proven safe in R5 4/4 runs),
// never cross-barrier global_load_lds (condemned). LDS double buffer 16KB/block;
// occupancy unchanged (4 blocks/CU, wave-limited). LDS layout = same linear copy
// as R6's gload16 staging -> identical fragment values -> absmax unchanged.
__global__ __launch_bounds__(256, 4) void attn_kernel(const bf16* __restrict__ Qb,
                                                      const bf16* __restrict__ Kf,
                                                      const bf16* __restrict__ Vf,
                                                      const int* __restrict__ wlp,
                                                      const int* __restrict__ wrp,
                                                      bf16* __restrict__ Yb) {
  __shared__ __align__(16) bf16 Ks[2][2048];  // double-buffered 32-key tiles (8KB)
  __shared__ __align__(16) bf16 Vs[2][2048];  // (8KB) -> 16KB/block
  const int tid = threadIdx.x;
  const int wl = wlp[0];
  const int wrc = min(wrp[0], 0);  // j<=i+wr && j<=i  ==>  j <= i+min(wr,0)
  const int blk = blockIdx.x;
  const int bkv = blk & 7;  // XCD round-robin -> K/V L2-resident per XCD
  const int b = bkv >> 2, kvh = bkv & 3;
  const int cm = 127 - (blk >> 3);  // chunk of 16 queries, big windows first
  const int w = tid >> 6, lane = tid & 63;
  const int q = lane >> 4, r0 = lane & 15;
  const int h = kvh * 4 + w;
  const int q0 = cm << 4;

  const bf16* qbase = Qb + (((size_t)b * 16 + h) * 2048 + q0 + r0) * 64;
  bf16x8 aq0 = *(const bf16x8*)(qbase + q * 8);
  bf16x8 aq1 = *(const bf16x8*)(qbase + 32 + q * 8);

  floatx4 O[4];
#pragma unroll
  for (int nt = 0; nt < 4; nt++) O[nt] = (floatx4){0.f, 0.f, 0.f, 0.f};
  floatx4 L = (floatx4){0.f, 0.f, 0.f, 0.f};

  const bf16 onev = (bf16)1.0f;
  const bf16x8 ones = {onev, onev, onev, onev, onev, onev, onev, onev};

  // all 4 waves share cm -> identical jlo/count -> no barrier divergence
  const int jlo = max(0, q0 - wl) & ~31;
  const int jhi = q0 + 15 + wrc;
  const int count = ((jhi - jlo) >> 5) + 1;
  const int tile0 = jlo >> 5;

  const bf16* kfb = Kf + ((size_t)(b * 4 + kvh) * 64) * 2048;
  const bf16* vfb = Vf + ((size_t)(b * 4 + kvh) * 64) * 2048;

  // prologue: thread tid copies elements [tid*8, tid*8+8) of tile0 into buf 0
  // (identical linear layout to the old gload16 staging: Ks[c*512 + lane*8])
  {
    uint4 kr = *(const uint4*)(kfb + (size_t)tile0 * 2048 + tid * 8);
    uint4 vr = *(const uint4*)(vfb + (size_t)tile0 * 2048 + tid * 8);
    *(uint4*)&Ks[0][tid * 8] = kr;
    *(uint4*)&Vs[0][tid * 8] = vr;
  }
  __syncthreads();

  int cur = 0;
  for (int t = 0; t < count; t++) {
    const int j0 = jlo + (t << 5);
    // T14 step 1: issue next tile's loads to registers (fly during compute below)
    const int tn = (t + 1 < count) ? tile0 + t + 1 : tile0 + t;
    uint4 kr = *(const uint4*)(kfb + (size_t)tn * 2048 + tid * 8);
    uint4 vr = *(const uint4*)(vfb + (size_t)tn * 2048 + tid * 8);

    // T14 step 2: compute current tile from LDS buf cur
    const bf16* Ku = &Ks[cur][0];
    const bf16* Vu = &Vs[cur][0];
    bf16x8 kf0 = *(const bf16x8*)&Ku[0 * 512 + lane * 8];
    bf16x8 kf1 = *(const bf16x8*)&Ku[1 * 512 + lane * 8];
    bf16x8 kf2 = *(const bf16x8*)&Ku[2 * 512 + lane * 8];
    bf16x8 kf3 = *(const bf16x8*)&Ku[3 * 512 + lane * 8];

    // S = K·Q^T - SHIFT_C (C-layout: row j-j0 = 4q+r (+16 for s1), col query = r0)
    floatx4 s0 = (floatx4){-SHIFT_C, -SHIFT_C, -SHIFT_C, -SHIFT_C};
    floatx4 s1 = s0;
    __builtin_amdgcn_s_setprio(1);
    s0 = mfma16(kf0, aq0, s0);
    s0 = mfma16(kf1, aq1, s0);
    s1 = mfma16(kf2, aq0, s1);
    s1 = mfma16(kf3, aq1, s1);
    __builtin_amdgcn_s_setprio(0);

    bf16x8 pa;
    if (j0 >= q0 + 15 - wl && j0 + 31 <= q0 + wrc) {
      // tile fully inside window for all 16 queries
#pragma unroll
      for (int r = 0; r < 4; r++) {
        pa[r] = (bf16)exp2f(s0[r]);
        pa[4 + r] = (bf16)exp2f(s1[r]);
      }
    } else {
      const int i = q0 + r0;
#pragma unroll
      for (int r = 0; r < 4; r++) {
        int ja = j0 + 4 * q + r, jb = ja + 16;
        bool va = (ja <= i + wrc) && (ja >= i - wl);
        bool vb = (jb <= i + wrc) && (jb >= i - wl);
        pa[r] = va ? (bf16)exp2f(s0[r]) : (bf16)0.f;
        pa[4 + r] = vb ? (bf16)exp2f(s1[r]) : (bf16)0.f;
      }
    }

    bf16x8 vf0 = *(const bf16x8*)&Vu[0 * 512 + lane * 8];
    bf16x8 vf1 = *(const bf16x8*)&Vu[1 * 512 + lane * 8];
    bf16x8 vf2 = *(const bf16x8*)&Vu[2 * 512 + lane * 8];
    bf16x8 vf3 = *(const bf16x8*)&Vu[3 * 512 + lane * 8];

    __builtin_amdgcn_s_setprio(1);
    L = mfma16(pa, ones, L);
    O[0] = mfma16(pa, vf0, O[0]);
    O[1] = mfma16(pa, vf1, O[1]);
    O[2] = mfma16(pa, vf2, O[2]);
    O[3] = mfma16(pa, vf3, O[3]);
    __builtin_amdgcn_s_setprio(0);

    // T14 step 3: all waves done reading buf cur^1 (last read 1 iter ago) and the
    // regs have arrived (compiler inserts vmcnt wait before the ds_write).
    __syncthreads();
    *(uint4*)&Ks[cur ^ 1][tid * 8] = kr;
    *(uint4*)&Vs[cur ^ 1][tid * 8] = vr;
    __syncthreads();  // writes visible to all waves
    cur ^= 1;
  }

  // O/L C-layout: row i-q0 = q*4+r, col d = nt*16+r0
  float inv[4];
#pragma unroll
  for (int r = 0; r < 4; r++) inv[r] = 1.f / L[r];
#pragma unroll
  for (int nt = 0; nt < 4; nt++)
#pragma unroll
    for (int r = 0; r < 4; r++) {
      int i = q0 + q * 4 + r;
      Yb[((size_t)b * 2048 + i) * 1024 + h * 64 + nt * 16 + r0] = (bf16)(O[nt][r] * inv[r]);
    }
}

// ---------------- launch ----------------
extern "C" void kernel_launch(void* const* d_in, const int* in_sizes, int n_in,
                              void* d_out, int out_size, void* d_ws, size_t ws_size,
                              hipStream_t stream) {
  const float* x     = (const float*)d_in[0];
  const float* ve    = (const float*)d_in[1];
  const float* cosb  = (const float*)d_in[2];
  const float* sinb  = (const float*)d_in[3];
  const float* Wq    = (const float*)d_in[4];
  const float* Wk    = (const float*)d_in[5];
  const float* Wv    = (const float*)d_in[6];
  const float* Wproj = (const float*)d_in[7];
  const float* Wgate = (const float*)d_in[8];
  const int* wl      = (const int*)d_in[9];
  const int* wr      = (const int*)d_in[10];

  char* ws = (char*)d_ws;
  bf16* Xb      = (bf16*)(ws);                 //  8,388,608 B: x bf16 [4096][1024]
  bf16* Wqkv_t  = (bf16*)(ws + 8388608);       //  3,145,728 B: [1536][1024]
  bf16* Wproj_t = (bf16*)(ws + 11534336);      //  2,097,152 B: [1024][1024]
  bf16* Qb      = (bf16*)(ws + 13631488);      //  8,388,608 B: [2][16][2048][64]
  bf16* Kf      = (bf16*)(ws + 22020096);      //  2,097,152 B: frag K [8][64 tiles][2048]
  bf16* Vf      = (bf16*)(ws + 24117248);      //  2,097,152 B: frag V
  bf16* Yb      = (bf16*)(ws + 26214400);      //  8,388,608 B: [4096][1024]
  float* gateb  = (float*)(ws + 34603008);     //     65,536 B: [2][4][2048]

  prep_kernel<<<4096 + 2560, 256, 0, stream>>>(x, Wgate, Wq, Wk, Wv, Wproj, Xb, gateb, Wqkv_t, Wproj_t);
  qkv_gemm_kernel<<<768, 256, 0, stream>>>(Xb, Wqkv_t, ve, cosb, sinb, gateb, Qb, Kf, Vf);
  attn_kernel<<<1024, 256, 0, stream>>>(Qb, Kf, Vf, wl, wr, Yb);
  proj_gemm_kernel<<<512, 256, 0, stream>>>(Yb, Wproj_t, (float*)d_out);
}

// Round 13
// 159.537 us; speedup vs baseline: 1.2271x; 1.0057x over previous
//
#include <hip/hip_runtime.h>

typedef __bf16 bf16;
typedef __bf16 bf16x4 __attribute__((ext_vector_type(4)));
typedef __bf16 bf16x8 __attribute__((ext_vector_type(8)));
typedef float floatx4 __attribute__((ext_vector_type(4)));

#define EPS 1.1920929e-07f
// q scale = D^-0.5 * log2(e) folded together (D=64 -> 0.125)
#define QSCALE (0.125f * 1.44269504088896f)
// fixed softmax shift: |q_eff . k| <= ||q_eff||*||k|| = (8*QSCALE)*8 = 11.5416
#define SHIFT_C 11.5416f

__device__ __forceinline__ floatx4 mfma16(bf16x8 a, bf16x8 b, floatx4 c) {
  return __builtin_amdgcn_mfma_f32_16x16x32_bf16(a, b, c, 0, 0, 0);
}

// async 16B global->LDS: HW writes ldsbase + lane*16; gptr is per-lane
__device__ __forceinline__ void gload16(const void* g, void* l) {
  __builtin_amdgcn_global_load_lds((const __attribute__((address_space(1))) unsigned int*)g,
                                   (__attribute__((address_space(3))) unsigned int*)l, 16, 0, 0);
}

// ---------------- merged prep: cast+gate (blocks <4096) | weight pack (blocks >=4096) ----
__global__ void prep_kernel(const float* __restrict__ x, const float* __restrict__ wgate,
                            const float* __restrict__ Wq, const float* __restrict__ Wk,
                            const float* __restrict__ Wv, const float* __restrict__ Wproj,
                            bf16* __restrict__ xb, float* __restrict__ gate,
                            bf16* __restrict__ out_qkv, bf16* __restrict__ out_proj) {
  __shared__ float tile[32][33];
  const int tid = threadIdx.x;
  if (blockIdx.x < 4096) {
    // ---- cast + gate: one block per token ----
    int t = blockIdx.x;
    const float* xr = x + (size_t)t * 1024;
    float4 v = *(const float4*)(xr + tid * 4);
    bf16x4 o = {(bf16)v.x, (bf16)v.y, (bf16)v.z, (bf16)v.w};
    *(bf16x4*)(xb + (size_t)t * 1024 + tid * 4) = o;
    if (tid < 64) {
      int c = (tid & 31) * 4;  // gate columns come from lanes 0..31 only
#pragma unroll
      for (int kv = 0; kv < 4; kv++) {
        float g = v.x * wgate[(c + 0) * 4 + kv] + v.y * wgate[(c + 1) * 4 + kv] +
                  v.z * wgate[(c + 2) * 4 + kv] + v.w * wgate[(c + 3) * 4 + kv];
        g += __shfl_xor(g, 1, 64);
        g += __shfl_xor(g, 2, 64);
        g += __shfl_xor(g, 4, 64);
        g += __shfl_xor(g, 8, 64);
        g += __shfl_xor(g, 16, 64);
        if (tid == 0) {
          int b = t >> 11, s = t & 2047;
          gate[((size_t)b * 4 + kv) * 2048 + s] = 2.f / (1.f + __expf(-g));
        }
      }
    }
  } else {
    // ---- weight pack: qkv (nx<48) + wproj (nx>=48) ----
    int j = blockIdx.x - 4096;
    int ky = j / 80;
    int nx = j - ky * 80;
    int k0 = ky * 32;
    int tx = tid & 31, ty = tid >> 5;
    if (nx < 48) {
      int n0 = nx * 32;
#pragma unroll
      for (int i = 0; i < 4; i++) {
        int k = k0 + ty + i * 8, n = n0 + tx;
        float v;
        if (n < 1024)      v = Wq[(size_t)k * 1024 + n];
        else if (n < 1280) v = Wk[(size_t)k * 256 + (n - 1024)];
        else               v = Wv[(size_t)k * 256 + (n - 1280)];
        tile[ty + i * 8][tx] = v;
      }
      __syncthreads();
#pragma unroll
      for (int i = 0; i < 4; i++) {
        int n = n0 + ty + i * 8, k = k0 + tx;
        out_qkv[(size_t)n * 1024 + k] = (bf16)tile[tx][ty + i * 8];
      }
    } else {
      int n0 = (nx - 48) * 32;
#pragma unroll
      for (int i = 0; i < 4; i++)
        tile[ty + i * 8][tx] = Wproj[(size_t)(k0 + ty + i * 8) * 1024 + n0 + tx];
      __syncthreads();
#pragma unroll
      for (int i = 0; i < 4; i++)
        out_proj[(size_t)(n0 + ty + i * 8) * 1024 + k0 + tx] = (bf16)tile[tx][ty + i * 8];
    }
  }
}

// ---------------- fused QKV GEMM: 128m x 64n tiles, BK=64, + RoPE/RMS/gate epilogue ----
// R6 known-good form. Single-buffer, 2 barriers/K-step, 24KB LDS, 3 blocks/CU.
// Measured ~660 TF (R9 probe) = 75% of m97-structure ceiling -> left as-is.
__global__ __launch_bounds__(256) void qkv_gemm_kernel(const bf16* __restrict__ A,
                                                       const bf16* __restrict__ Bt,
                                                       const float* __restrict__ ve,
                                                       const float* __restrict__ cosb,
                                                       const float* __restrict__ sinb,
                                                       const float* __restrict__ gate,
                                                       bf16* __restrict__ Qb,
                                                       bf16* __restrict__ Kf,
                                                       bf16* __restrict__ Vf) {
  __shared__ __align__(16) char smem[24576];  // As 16K (2 halves x 128 x 32) + Bs 8K; epilogue Ep 128x72 bf16
  bf16* As = (bf16*)smem;
  bf16* Bs = (bf16*)(smem + 16384);
  bf16* Ep = (bf16*)smem;
  const int K = 1024;
  const int tid = threadIdx.x;
  // XCD-chunked bijective swizzle (768 % 8 == 0)
  const int orig = blockIdx.x;
  const int lid = (orig & 7) * 96 + (orig >> 3);
  const int tile = lid % 24;        // n-tile
  const int m0 = (lid / 24) * 128, n0 = tile * 64;
  const int w = tid >> 6, lane = tid & 63;
  const int q = lane >> 4, r0 = lane & 15;
  const int lrow = lane >> 2, lcol = (lane & 3) * 8;
  const int b = m0 >> 11, s0 = m0 & 2047;

  floatx4 acc[2][4];
#pragma unroll
  for (int i = 0; i < 2; i++)
#pragma unroll
    for (int j = 0; j < 4; j++) acc[i][j] = (floatx4){0.f, 0.f, 0.f, 0.f};

  for (int k0 = 0; k0 < K; k0 += 64) {
    __syncthreads();
    // A: 16 gloads (half s, row-block rb): wave w issues g = w*4..w*4+3
#pragma unroll
    for (int i = 0; i < 4; i++) {
      int g = w * 4 + i, s = g >> 3, rb = g & 7;
      gload16(A + (size_t)(m0 + rb * 16 + lrow) * K + k0 + s * 32 + lcol, &As[s * 4096 + rb * 512]);
    }
    // B: 8 gloads: wave w issues g = w*2, w*2+1
#pragma unroll
    for (int i = 0; i < 2; i++) {
      int g = w * 2 + i, s = g >> 2, rb = g & 3;
      gload16(Bt + (size_t)(n0 + rb * 16 + lrow) * K + k0 + s * 32 + lcol, &Bs[s * 2048 + rb * 512]);
    }
    __syncthreads();
#pragma unroll
    for (int s = 0; s < 2; s++) {
      bf16x8 af[2], bfr[4];
#pragma unroll
      for (int mt = 0; mt < 2; mt++) af[mt] = *(const bf16x8*)&As[s * 4096 + (w * 32 + mt * 16 + r0) * 32 + q * 8];
#pragma unroll
      for (int nt = 0; nt < 4; nt++) bfr[nt] = *(const bf16x8*)&Bs[s * 2048 + (nt * 16 + r0) * 32 + q * 8];
#pragma unroll
      for (int mt = 0; mt < 2; mt++)
#pragma unroll
        for (int nt = 0; nt < 4; nt++)
          acc[mt][nt] = mfma16(af[mt], bfr[nt], acc[mt][nt]);
    }
  }
  __syncthreads();  // all LDS reads done; Ep reuses the space

  // lane owns rows w*32 + mt*16 + q*4 + r (token - m0), d = nt*16 + r0
  if (tile < 16) {
    // ---- Q: rope -> rms -> *QSCALE -> Ep -> coalesced Qb copy ----
    const int h = tile;
#pragma unroll
    for (int mt = 0; mt < 2; mt++) {
      float rvv[4][4];
#pragma unroll
      for (int ntp = 0; ntp < 2; ntp++) {
        int d31 = ntp * 16 + r0;
#pragma unroll
        for (int r = 0; r < 4; r++) {
          int s = s0 + w * 32 + mt * 16 + q * 4 + r;
          float c = cosb[s * 32 + d31], sn = sinb[s * 32 + d31];
          float v1 = acc[mt][ntp][r], v2 = acc[mt][ntp + 2][r];
          rvv[ntp][r] = v1 * c + v2 * sn;
          rvv[ntp + 2][r] = v2 * c - v1 * sn;
        }
      }
#pragma unroll
      for (int r = 0; r < 4; r++) {
        float ss = 0.f;
#pragma unroll
        for (int nt = 0; nt < 4; nt++) ss += rvv[nt][r] * rvv[nt][r];
        ss += __shfl_xor(ss, 1, 64);
        ss += __shfl_xor(ss, 2, 64);
        ss += __shfl_xor(ss, 4, 64);
        ss += __shfl_xor(ss, 8, 64);
        float sc = rsqrtf(ss * (1.f / 64.f) + EPS) * QSCALE;
        int row = w * 32 + mt * 16 + q * 4 + r;
#pragma unroll
        for (int nt = 0; nt < 4; nt++)
          Ep[row * 72 + nt * 16 + r0] = (bf16)(rvv[nt][r] * sc);
      }
    }
    __syncthreads();
#pragma unroll
    for (int p = 0; p < 4; p++) {
      int g = p * 256 + tid;
      int row = g >> 3, chunk = g & 7;
      *(uint4*)&Qb[(((size_t)b * 16 + h) * 2048 + s0 + row) * 64 + chunk * 8] =
          *(const uint4*)&Ep[row * 72 + chunk * 8];
    }
  } else if (tile < 20) {
    // ---- K: rope -> rms -> Ep -> Kf fragment layout ----
    const int kv = tile - 16;
#pragma unroll
    for (int mt = 0; mt < 2; mt++) {
      float rvv[4][4];
#pragma unroll
      for (int ntp = 0; ntp < 2; ntp++) {
        int d31 = ntp * 16 + r0;
#pragma unroll
        for (int r = 0; r < 4; r++) {
          int s = s0 + w * 32 + mt * 16 + q * 4 + r;
          float c = cosb[s * 32 + d31], sn = sinb[s * 32 + d31];
          float v1 = acc[mt][ntp][r], v2 = acc[mt][ntp + 2][r];
          rvv[ntp][r] = v1 * c + v2 * sn;
          rvv[ntp + 2][r] = v2 * c - v1 * sn;
        }
      }
#pragma unroll
      for (int r = 0; r < 4; r++) {
        float ss = 0.f;
#pragma unroll
        for (int nt = 0; nt < 4; nt++) ss += rvv[nt][r] * rvv[nt][r];
        ss += __shfl_xor(ss, 1, 64);
        ss += __shfl_xor(ss, 2, 64);
        ss += __shfl_xor(ss, 4, 64);
        ss += __shfl_xor(ss, 8, 64);
        float sc = rsqrtf(ss * (1.f / 64.f) + EPS);
        int row = w * 32 + mt * 16 + q * 4 + r;
#pragma unroll
        for (int nt = 0; nt < 4; nt++)
          Ep[row * 72 + nt * 16 + r0] = (bf16)(rvv[nt][r] * sc);
      }
    }
    __syncthreads();
    // each wave extracts frags for its own 32-key sub-tile
    {
      int tk = (s0 >> 5) + w;
      size_t tb = ((size_t)(b * 4 + kv) * 64 + tk) * 2048;
#pragma unroll
      for (int u = 0; u < 4; u++) {
        int joff = (u >= 2) ? 16 : 0, doff = (u & 1) * 32;
        bf16x8 f = *(const bf16x8*)&Ep[(w * 32 + joff + r0) * 72 + doff + q * 8];
        *(bf16x8*)&Kf[tb + u * 512 + lane * 8] = f;
      }
    }
  } else {
    // ---- V: + gate*ve -> Ep -> Vf fragment layout ----
    const int kv = tile - 20;
    const float* gbase = gate + ((size_t)b * 4 + kv) * 2048;
#pragma unroll
    for (int mt = 0; mt < 2; mt++) {
#pragma unroll
      for (int r = 0; r < 4; r++) {
        int row = w * 32 + mt * 16 + q * 4 + r;
        float gg = gbase[s0 + row];
#pragma unroll
        for (int nt = 0; nt < 4; nt++) {
          int d = nt * 16 + r0;
          float vv = acc[mt][nt][r] + gg * ve[(size_t)(m0 + row) * 256 + kv * 64 + d];
          Ep[row * 72 + d] = (bf16)vv;
        }
      }
    }
    __syncthreads();
    {
      int tk = (s0 >> 5) + w;
      size_t tb = ((size_t)(b * 4 + kv) * 64 + tk) * 2048;
#pragma unroll
      for (int nt = 0; nt < 4; nt++) {
        bf16 tmp[8];
#pragma unroll
        for (int e = 0; e < 8; e++) {
          int jl = w * 32 + (e >> 2) * 16 + 4 * q + (e & 3);
          tmp[e] = Ep[jl * 72 + nt * 16 + r0];
        }
        *(uint4*)&Vf[tb + nt * 512 + lane * 8] = *(uint4*)tmp;
      }
    }
  }
}

// ---------------- proj GEMM: 128m x 64n, BK=64, fp32 out, XCD-chunked swizzle ------
// Measured ~660 TF (R9 probe) -> left as-is.
__global__ __launch_bounds__(256) void proj_gemm_kernel(const bf16* __restrict__ A,
                                                        const bf16* __restrict__ Bt,
                                                        float* __restrict__ Cout) {
  __shared__ __align__(16) bf16 As[2 * 128 * 32];
  __shared__ __align__(16) bf16 Bs[2 * 64 * 32];
  const int K = 1024, N = 1024;
  const int tid = threadIdx.x;
  // XCD-chunked bijective swizzle (512 % 8 == 0): XCD k -> 4 consecutive m-panels
  const int orig = blockIdx.x;
  const int lid = (orig & 7) * 64 + (orig >> 3);
  const int m0 = (lid / 16) * 128, n0 = (lid % 16) * 64;
  const int w = tid >> 6, lane = tid & 63;
  const int q = lane >> 4, r0 = lane & 15;
  const int lrow = lane >> 2, lcol = (lane & 3) * 8;

  floatx4 acc[2][4];
#pragma unroll
  for (int i = 0; i < 2; i++)
#pragma unroll
    for (int j = 0; j < 4; j++) acc[i][j] = (floatx4){0.f, 0.f, 0.f, 0.f};

  for (int k0 = 0; k0 < K; k0 += 64) {
    __syncthreads();
#pragma unroll
    for (int i = 0; i < 4; i++) {
      int g = w * 4 + i, s = g >> 3, rb = g & 7;
      gload16(A + (size_t)(m0 + rb * 16 + lrow) * K + k0 + s * 32 + lcol, &As[s * 4096 + rb * 512]);
    }
#pragma unroll
    for (int i = 0; i < 2; i++) {
      int g = w * 2 + i, s = g >> 2, rb = g & 3;
      gload16(Bt + (size_t)(n0 + rb * 16 + lrow) * K + k0 + s * 32 + lcol, &Bs[s * 2048 + rb * 512]);
    }
    __syncthreads();
#pragma unroll
    for (int s = 0; s < 2; s++) {
      bf16x8 af[2], bfr[4];
#pragma unroll
      for (int mt = 0; mt < 2; mt++) af[mt] = *(const bf16x8*)&As[s * 4096 + (w * 32 + mt * 16 + r0) * 32 + q * 8];
#pragma unroll
      for (int nt = 0; nt < 4; nt++) bfr[nt] = *(const bf16x8*)&Bs[s * 2048 + (nt * 16 + r0) * 32 + q * 8];
#pragma unroll
      for (int mt = 0; mt < 2; mt++)
#pragma unroll
        for (int nt = 0; nt < 4; nt++)
          acc[mt][nt] = mfma16(af[mt], bfr[nt], acc[mt][nt]);
    }
  }
#pragma unroll
  for (int mt = 0; mt < 2; mt++)
#pragma unroll
    for (int nt = 0; nt < 4; nt++)
#pragma unroll
      for (int r = 0; r < 4; r++) {
        int row = m0 + w * 32 + mt * 16 + q * 4 + r;
        int col = n0 + nt * 16 + r0;
        Cout[(size_t)row * N + col] = acc[mt][nt][r];
      }
}

// ---------------- flash attention: T14 async-STAGE split, double-buffered LDS ------
// R11 verified-best form (160.4us). 2 barriers/tile: compute -> barrier -> ds_write
// -> barrier. Write is bracketed by barriers on BOTH sides — airtight vs the
// condemned single-barrier triple-buffer (R12: raced, absmax 0.48 post-timing).
// T14: next tile's K/V loads issue to REGISTERS before compute (HBM/L2 latency
// hides under MFMA+exp); consumed as ds_writes after the barrier. Cross-barrier
// traffic is registers only. 16KB LDS/block, 4 blocks/CU.
__global__ __launch_bounds__(256, 4) void attn_kernel(const bf16* __restrict__ Qb,
                                                      const bf16* __restrict__ Kf,
                                                      const bf16* __restrict__ Vf,
                                                      const int* __restrict__ wlp,
                                                      const int* __restrict__ wrp,
                                                      bf16* __restrict__ Yb) {
  __shared__ __align__(16) bf16 Ks[2][2048];  // double-buffered 32-key tiles (8KB)
  __shared__ __align__(16) bf16 Vs[2][2048];  // (8KB) -> 16KB/block
  const int tid = threadIdx.x;
  const int wl = wlp[0];
  const int wrc = min(wrp[0], 0);  // j<=i+wr && j<=i  ==>  j <= i+min(wr,0)
  const int blk = blockIdx.x;
  const int bkv = blk & 7;  // XCD round-robin -> K/V L2-resident per XCD
  const int b = bkv >> 2, kvh = bkv & 3;
  const int cm = 127 - (blk >> 3);  // chunk of 16 queries, big windows first
  const int w = tid >> 6, lane = tid & 63;
  const int q = lane >> 4, r0 = lane & 15;
  const int h = kvh * 4 + w;
  const int q0 = cm << 4;

  const bf16* qbase = Qb + (((size_t)b * 16 + h) * 2048 + q0 + r0) * 64;
  bf16x8 aq0 = *(const bf16x8*)(qbase + q * 8);
  bf16x8 aq1 = *(const bf16x8*)(qbase + 32 + q * 8);

  floatx4 O[4];
#pragma unroll
  for (int nt = 0; nt < 4; nt++) O[nt] = (floatx4){0.f, 0.f, 0.f, 0.f};
  floatx4 L = (floatx4){0.f, 0.f, 0.f, 0.f};

  const bf16 onev = (bf16)1.0f;
  const bf16x8 ones = {onev, onev, onev, onev, onev, onev, onev, onev};

  // all 4 waves share cm -> identical jlo/count -> no barrier divergence
  const int jlo = max(0, q0 - wl) & ~31;
  const int jhi = q0 + 15 + wrc;
  const int count = ((jhi - jlo) >> 5) + 1;
  const int tile0 = jlo >> 5;

  const bf16* kfb = Kf + ((size_t)(b * 4 + kvh) * 64) * 2048;
  const bf16* vfb = Vf + ((size_t)(b * 4 + kvh) * 64) * 2048;

  // prologue: thread tid copies elements [tid*8, tid*8+8) of tile0 into buf 0
  // (identical linear layout to the gload16 staging: Ks[c*512 + lane*8])
  {
    uint4 kr = *(const uint4*)(kfb + (size_t)tile0 * 2048 + tid * 8);
    uint4 vr = *(const uint4*)(vfb + (size_t)tile0 * 2048 + tid * 8);
    *(uint4*)&Ks[0][tid * 8] = kr;
    *(uint4*)&Vs[0][tid * 8] = vr;
  }
  __syncthreads();

  int cur = 0;
  for (int t = 0; t < count; t++) {
    const int j0 = jlo + (t << 5);
    // T14 step 1: issue next tile's loads to registers (fly during compute below)
    const int tn = (t + 1 < count) ? tile0 + t + 1 : tile0 + t;
    uint4 kr = *(const uint4*)(kfb + (size_t)tn * 2048 + tid * 8);
    uint4 vr = *(const uint4*)(vfb + (size_t)tn * 2048 + tid * 8);

    // T14 step 2: compute current tile from LDS buf cur
    const bf16* Ku = &Ks[cur][0];
    const bf16* Vu = &Vs[cur][0];
    bf16x8 kf0 = *(const bf16x8*)&Ku[0 * 512 + lane * 8];
    bf16x8 kf1 = *(const bf16x8*)&Ku[1 * 512 + lane * 8];
    bf16x8 kf2 = *(const bf16x8*)&Ku[2 * 512 + lane * 8];
    bf16x8 kf3 = *(const bf16x8*)&Ku[3 * 512 + lane * 8];

    // S = K·Q^T - SHIFT_C (C-layout: row j-j0 = 4q+r (+16 for s1), col query = r0)
    floatx4 s0 = (floatx4){-SHIFT_C, -SHIFT_C, -SHIFT_C, -SHIFT_C};
    floatx4 s1 = s0;
    __builtin_amdgcn_s_setprio(1);
    s0 = mfma16(kf0, aq0, s0);
    s0 = mfma16(kf1, aq1, s0);
    s1 = mfma16(kf2, aq0, s1);
    s1 = mfma16(kf3, aq1, s1);
    __builtin_amdgcn_s_setprio(0);

    bf16x8 pa;
    if (j0 >= q0 + 15 - wl && j0 + 31 <= q0 + wrc) {
      // tile fully inside window for all 16 queries
#pragma unroll
      for (int r = 0; r < 4; r++) {
        pa[r] = (bf16)exp2f(s0[r]);
        pa[4 + r] = (bf16)exp2f(s1[r]);
      }
    } else {
      const int i = q0 + r0;
#pragma unroll
      for (int r = 0; r < 4; r++) {
        int ja = j0 + 4 * q + r, jb = ja + 16;
        bool va = (ja <= i + wrc) && (ja >= i - wl);
        bool vb = (jb <= i + wrc) && (jb >= i - wl);
        pa[r] = va ? (bf16)exp2f(s0[r]) : (bf16)0.f;
        pa[4 + r] = vb ? (bf16)exp2f(s1[r]) : (bf16)0.f;
      }
    }

    bf16x8 vf0 = *(const bf16x8*)&Vu[0 * 512 + lane * 8];
    bf16x8 vf1 = *(const bf16x8*)&Vu[1 * 512 + lane * 8];
    bf16x8 vf2 = *(const bf16x8*)&Vu[2 * 512 + lane * 8];
    bf16x8 vf3 = *(const bf16x8*)&Vu[3 * 512 + lane * 8];

    __builtin_amdgcn_s_setprio(1);
    L = mfma16(pa, ones, L);
    O[0] = mfma16(pa, vf0, O[0]);
    O[1] = mfma16(pa, vf1, O[1]);
    O[2] = mfma16(pa, vf2, O[2]);
    O[3] = mfma16(pa, vf3, O[3]);
    __builtin_amdgcn_s_setprio(0);

    // T14 step 3: all waves done reading buf cur^1 (last read 1 iter ago) and the
    // regs have arrived (compiler inserts vmcnt wait before the ds_write).
    __syncthreads();
    *(uint4*)&Ks[cur ^ 1][tid * 8] = kr;
    *(uint4*)&Vs[cur ^ 1][tid * 8] = vr;
    __syncthreads();  // writes visible to all waves
    cur ^= 1;
  }

  // O/L C-layout: row i-q0 = q*4+r, col d = nt*16+r0
  float inv[4];
#pragma unroll
  for (int r = 0; r < 4; r++) inv[r] = 1.f / L[r];
#pragma unroll
  for (int nt = 0; nt < 4; nt++)
#pragma unroll
    for (int r = 0; r < 4; r++) {
      int i = q0 + q * 4 + r;
      Yb[((size_t)b * 2048 + i) * 1024 + h * 64 + nt * 16 + r0] = (bf16)(O[nt][r] * inv[r]);
    }
}

// ---------------- launch ----------------
extern "C" void kernel_launch(void* const* d_in, const int* in_sizes, int n_in,
                              void* d_out, int out_size, void* d_ws, size_t ws_size,
                              hipStream_t stream) {
  const float* x     = (const float*)d_in[0];
  const float* ve    = (const float*)d_in[1];
  const float* cosb  = (const float*)d_in[2];
  const float* sinb  = (const float*)d_in[3];
  const float* Wq    = (const float*)d_in[4];
  const float* Wk    = (const float*)d_in[5];
  const float* Wv    = (const float*)d_in[6];
  const float* Wproj = (const float*)d_in[7];
  const float* Wgate = (const float*)d_in[8];
  const int* wl      = (const int*)d_in[9];
  const int* wr      = (const int*)d_in[10];

  char* ws = (char*)d_ws;
  bf16* Xb      = (bf16*)(ws);                 //  8,388,608 B: x bf16 [4096][1024]
  bf16* Wqkv_t  = (bf16*)(ws + 8388608);       //  3,145,728 B: [1536][1024]
  bf16* Wproj_t = (bf16*)(ws + 11534336);      //  2,097,152 B: [1024][1024]
  bf16* Qb      = (bf16*)(ws + 13631488);      //  8,388,608 B: [2][16][2048][64]
  bf16* Kf      = (bf16*)(ws + 22020096);      //  2,097,152 B: frag K [8][64 tiles][2048]
  bf16* Vf      = (bf16*)(ws + 24117248);      //  2,097,152 B: frag V
  bf16* Yb      = (bf16*)(ws + 26214400);      //  8,388,608 B: [4096][1024]
  float* gateb  = (float*)(ws + 34603008);     //     65,536 B: [2][4][2048]

  prep_kernel<<<4096 + 2560, 256, 0, stream>>>(x, Wgate, Wq, Wk, Wv, Wproj, Xb, gateb, Wqkv_t, Wproj_t);
  qkv_gemm_kernel<<<768, 256, 0, stream>>>(Xb, Wqkv_t, ve, cosb, sinb, gateb, Qb, Kf, Vf);
  attn_kernel<<<1024, 256, 0, stream>>>(Qb, Kf, Vf, wl, wr, Yb);
  proj_gemm_kernel<<<512, 256, 0, stream>>>(Yb, Wproj_t, (float*)d_out);
}